// Round 1
// baseline (758.826 us; speedup 1.0000x reference)
//
#include <hip/hip_runtime.h>

// ---------------------------------------------------------------------------
// GraphSAGE 2-layer forward on MI355X.
//   Layer l: out = deg_inv * segsum((x@Wl.T)[src] -> dst) + x@Wr.T + b
// Strategy: GEMM first (linearity), then CSR-based per-node aggregation
// (wave per dst node, lanes = channels). No float atomics.
// ---------------------------------------------------------------------------

__device__ __forceinline__ int edge_at(const void* ep, int is64, long long idx) {
  if (is64) return (int)((const long long*)ep)[idx];
  return ((const int*)ep)[idx];
}

// Detect whether edge_index is int64 (odd int32 words are all-zero hi words)
// or int32. Writes 1 to *flag if int64, else 0.
__global__ __launch_bounds__(256) void detect_kernel(const int* e32, int* flag) {
  __shared__ int s;
  if (threadIdx.x == 0) s = 1;
  __syncthreads();
  if (e32[2 * threadIdx.x + 1] != 0) s = 0;  // benign race, all writers write 0
  __syncthreads();
  if (threadIdx.x == 0) *flag = s;
}

__global__ __launch_bounds__(256) void hist_kernel(const void* edges, const int* flag,
                                                   int* deg, long long E) {
  long long e = (long long)blockIdx.x * 256 + threadIdx.x;
  if (e >= E) return;
  int is64 = *flag;
  int dst = edge_at(edges, is64, E + e);
  atomicAdd(&deg[dst], 1);
}

__global__ __launch_bounds__(256) void scan_reduce_kernel(const int* __restrict__ deg,
                                                          int* __restrict__ blockSums, int N) {
  __shared__ int sm[256];
  int base = blockIdx.x * 1024;
  int t = threadIdx.x;
  int s = 0;
  for (int i = t; i < 1024; i += 256) {
    int gi = base + i;
    if (gi < N) s += deg[gi];
  }
  sm[t] = s;
  __syncthreads();
  for (int o = 128; o > 0; o >>= 1) {
    if (t < o) sm[t] += sm[t + o];
    __syncthreads();
  }
  if (t == 0) blockSums[blockIdx.x] = sm[0];
}

__global__ void scan_offsets_kernel(const int* __restrict__ blockSums, int* __restrict__ blockOffs,
                                    int nb, int* __restrict__ row_ptr, int N) {
  if (threadIdx.x == 0 && blockIdx.x == 0) {
    int acc = 0;
    for (int i = 0; i < nb; ++i) { blockOffs[i] = acc; acc += blockSums[i]; }
    row_ptr[N] = acc;
  }
}

__global__ __launch_bounds__(1024) void scan_final_kernel(const int* __restrict__ deg,
                                                          const int* __restrict__ blockOffs,
                                                          int* __restrict__ row_ptr,
                                                          int* __restrict__ cursor,
                                                          float* __restrict__ deg_inv, int N) {
  __shared__ int sm[1024];
  int t = threadIdx.x;
  int gi = blockIdx.x * 1024 + t;
  int v = (gi < N) ? deg[gi] : 0;
  sm[t] = v;
  __syncthreads();
  for (int o = 1; o < 1024; o <<= 1) {
    int x = (t >= o) ? sm[t - o] : 0;
    __syncthreads();
    sm[t] += x;
    __syncthreads();
  }
  if (gi < N) {
    int excl = sm[t] - v;  // exclusive prefix within block
    int rp = blockOffs[blockIdx.x] + excl;
    row_ptr[gi] = rp;
    cursor[gi] = rp;
    deg_inv[gi] = (v > 0) ? (1.0f / (float)v) : 0.0f;
  }
}

__global__ __launch_bounds__(256) void fill_kernel(const void* edges, const int* flag,
                                                   int* cursor, int* __restrict__ sorted_src,
                                                   long long E) {
  long long e = (long long)blockIdx.x * 256 + threadIdx.x;
  if (e >= E) return;
  int is64 = *flag;
  int src = edge_at(edges, is64, e);
  int dst = edge_at(edges, is64, E + e);
  int pos = atomicAdd(&cursor[dst], 1);
  sorted_src[pos] = src;
}

// C[N, ncols] = X[N,128] @ [Wl; Wr]^T, K = 128 fixed.
// col j < split -> Wl row j; else Wr row (j - split). Tiles 64x64, 256 thr, 4x4/thread.
__global__ __launch_bounds__(256) void gemm_kernel(const float* __restrict__ X,
                                                   const float* __restrict__ Wl,
                                                   const float* __restrict__ Wr,
                                                   float* __restrict__ C,
                                                   int N, int ncols, int split) {
  __shared__ float Xs[64][132];
  __shared__ float Ws[64][132];
  int rb = blockIdx.x * 64;
  int cb = blockIdx.y * 64;
  int tid = threadIdx.x;

  for (int i = tid; i < 64 * 32; i += 256) {
    int r = i >> 5;
    int c4 = (i & 31) * 4;
    int gr = rb + r;
    float4 v = make_float4(0.f, 0.f, 0.f, 0.f);
    if (gr < N) v = *(const float4*)(X + (long long)gr * 128 + c4);
    *(float4*)&Xs[r][c4] = v;
    int gc = cb + r;
    const float* wrow = (gc < split) ? (Wl + (long long)gc * 128)
                                     : (Wr + (long long)(gc - split) * 128);
    *(float4*)&Ws[r][c4] = *(const float4*)(wrow + c4);
  }
  __syncthreads();

  int tx = tid & 15, ty = tid >> 4;
  float acc[4][4];
#pragma unroll
  for (int i = 0; i < 4; ++i)
#pragma unroll
    for (int j = 0; j < 4; ++j) acc[i][j] = 0.f;

#pragma unroll 4
  for (int k = 0; k < 128; k += 4) {
    float4 a[4], b[4];
#pragma unroll
    for (int i = 0; i < 4; ++i) a[i] = *(const float4*)&Xs[ty * 4 + i][k];
#pragma unroll
    for (int j = 0; j < 4; ++j) b[j] = *(const float4*)&Ws[tx * 4 + j][k];
#pragma unroll
    for (int i = 0; i < 4; ++i)
#pragma unroll
      for (int j = 0; j < 4; ++j)
        acc[i][j] += a[i].x * b[j].x + a[i].y * b[j].y + a[i].z * b[j].z + a[i].w * b[j].w;
  }

#pragma unroll
  for (int i = 0; i < 4; ++i) {
    int gr = rb + ty * 4 + i;
    if (gr < N) {
      float4 o = make_float4(acc[i][0], acc[i][1], acc[i][2], acc[i][3]);
      *(float4*)(C + (long long)gr * ncols + cb + tx * 4) = o;
    }
  }
}

// Layer-1 aggregate + combine + ReLU. One wave per node, lane handles 2 channels.
// t1: [N,256] = [x@W1_l.T | x@W1_r.T]; h: [N,128]
__global__ __launch_bounds__(256) void agg1_kernel(const float* __restrict__ t1,
                                                   const int* __restrict__ row_ptr,
                                                   const int* __restrict__ sorted_src,
                                                   const float* __restrict__ deg_inv,
                                                   const float* __restrict__ b1,
                                                   float* __restrict__ h, int N) {
  int node = (int)(((long long)blockIdx.x * 256 + threadIdx.x) >> 6);
  int lane = threadIdx.x & 63;
  if (node >= N) return;
  int beg = row_ptr[node], end = row_ptr[node + 1];
  float sx = 0.f, sy = 0.f;
  for (int e = beg; e < end; ++e) {
    int s = sorted_src[e];
    float2 v = *(const float2*)(t1 + (long long)s * 256 + lane * 2);
    sx += v.x;
    sy += v.y;
  }
  float di = deg_inv[node];
  float2 tr = *(const float2*)(t1 + (long long)node * 256 + 128 + lane * 2);
  float2 bb = *(const float2*)(b1 + lane * 2);
  float hx = fmaxf(sx * di + tr.x + bb.x, 0.f);
  float hy = fmaxf(sy * di + tr.y + bb.y, 0.f);
  *(float2*)(h + (long long)node * 128 + lane * 2) = make_float2(hx, hy);
}

// Layer-2 aggregate + combine. One wave per node, lane = channel (64 ch).
// t3: [N,128] = [h@W2_l.T | h@W2_r.T]; out: [N,64]
__global__ __launch_bounds__(256) void agg2_kernel(const float* __restrict__ t3,
                                                   const int* __restrict__ row_ptr,
                                                   const int* __restrict__ sorted_src,
                                                   const float* __restrict__ deg_inv,
                                                   const float* __restrict__ b2,
                                                   float* __restrict__ out, int N) {
  int node = (int)(((long long)blockIdx.x * 256 + threadIdx.x) >> 6);
  int lane = threadIdx.x & 63;
  if (node >= N) return;
  int beg = row_ptr[node], end = row_ptr[node + 1];
  float s = 0.f;
  for (int e = beg; e < end; ++e) {
    int sn = sorted_src[e];
    s += t3[(long long)sn * 128 + lane];
  }
  float r = s * deg_inv[node] + t3[(long long)node * 128 + 64 + lane] + b2[lane];
  out[(long long)node * 64 + lane] = r;
}

extern "C" void kernel_launch(void* const* d_in, const int* in_sizes, int n_in,
                              void* d_out, int out_size, void* d_ws, size_t ws_size,
                              hipStream_t stream) {
  const float* x = (const float*)d_in[0];
  const void* edges = d_in[1];
  const float* W1l = (const float*)d_in[2];
  const float* W1r = (const float*)d_in[3];
  const float* b1 = (const float*)d_in[4];
  const float* W2l = (const float*)d_in[5];
  const float* W2r = (const float*)d_in[6];
  const float* b2 = (const float*)d_in[7];
  float* out = (float*)d_out;

  int N = in_sizes[0] / 128;
  long long E = (long long)in_sizes[1] / 2;
  int NB = (N + 1023) / 1024;

  // workspace carve-up (256B aligned)
  auto align = [](size_t v) { return (v + 255) & ~(size_t)255; };
  char* ws = (char*)d_ws;
  size_t o = 0;
  int* flag = (int*)(ws + o);        o += align(sizeof(int));
  int* deg = (int*)(ws + o);         o += align((size_t)N * 4);
  int* blockSums = (int*)(ws + o);   o += align((size_t)NB * 4);
  int* blockOffs = (int*)(ws + o);   o += align((size_t)NB * 4);
  int* row_ptr = (int*)(ws + o);     o += align((size_t)(N + 1) * 4);
  int* cursor = (int*)(ws + o);      o += align((size_t)N * 4);
  float* deg_inv = (float*)(ws + o); o += align((size_t)N * 4);
  int* sorted_src = (int*)(ws + o);  o += align((size_t)E * 4);
  float* t1 = (float*)(ws + o);      o += align((size_t)N * 256 * 4);
  float* h = (float*)(ws + o);       o += align((size_t)N * 128 * 4);
  float* t3 = t1;  // alias: t1 dead once h is computed

  hipMemsetAsync(deg, 0, (size_t)N * 4, stream);
  detect_kernel<<<1, 256, 0, stream>>>((const int*)edges, flag);

  int eblocks = (int)((E + 255) / 256);
  hist_kernel<<<eblocks, 256, 0, stream>>>(edges, flag, deg, E);
  scan_reduce_kernel<<<NB, 256, 0, stream>>>(deg, blockSums, N);
  scan_offsets_kernel<<<1, 64, 0, stream>>>(blockSums, blockOffs, NB, row_ptr, N);
  scan_final_kernel<<<NB, 1024, 0, stream>>>(deg, blockOffs, row_ptr, cursor, deg_inv, N);
  fill_kernel<<<eblocks, 256, 0, stream>>>(edges, flag, cursor, sorted_src, E);

  // Layer 1: t1 = x @ [W1_l | W1_r]^T  (ncols=256, split=128)
  gemm_kernel<<<dim3((N + 63) / 64, 4), 256, 0, stream>>>(x, W1l, W1r, t1, N, 256, 128);
  agg1_kernel<<<(N + 3) / 4, 256, 0, stream>>>(t1, row_ptr, sorted_src, deg_inv, b1, h, N);

  // Layer 2: t3 = h @ [W2_l | W2_r]^T  (ncols=128, split=64)
  gemm_kernel<<<dim3((N + 63) / 64, 2), 256, 0, stream>>>(h, W2l, W2r, t3, N, 128, 64);
  agg2_kernel<<<(N + 3) / 4, 256, 0, stream>>>(t3, row_ptr, sorted_src, deg_inv, b2, out, N);
}

// Round 2
// 476.498 us; speedup vs baseline: 1.5925x; 1.5925x over previous
//
#include <hip/hip_runtime.h>

// ---------------------------------------------------------------------------
// GraphSAGE 2-layer forward on MI355X (gfx950).
//   Layer l: out = deg_inv * segsum((x@Wl.T)[src] -> dst) + x@Wr.T + b
// GEMM-first (linearity), bf16 MFMA GEMMs with f32 accumulate, CSR-based
// per-node mean aggregation (wave per dst node). No float atomics.
// Gathered halves (t1l/t3l) + h stored bf16; self halves (t1r/t3r) f32.
// ---------------------------------------------------------------------------

typedef float f32x4 __attribute__((ext_vector_type(4)));
typedef short bf16x8 __attribute__((ext_vector_type(8)));
typedef unsigned short u16;
typedef unsigned short u16x2 __attribute__((ext_vector_type(2)));
typedef unsigned short u16x4 __attribute__((ext_vector_type(4)));
typedef unsigned short u16x8 __attribute__((ext_vector_type(8)));

__device__ __forceinline__ u16 f2b(float f) {  // f32 -> bf16 RNE (finite inputs)
  unsigned u = __builtin_bit_cast(unsigned, f);
  u += 0x7FFFu + ((u >> 16) & 1u);
  return (u16)(u >> 16);
}
__device__ __forceinline__ float b2f(u16 s) {
  unsigned u = (unsigned)s << 16;
  return __builtin_bit_cast(float, u);
}

__device__ __forceinline__ int edge_at(const void* ep, int is64, long long idx) {
  if (is64) return (int)((const long long*)ep)[idx];
  return ((const int*)ep)[idx];
}

// int64 vs int32 edge_index detection (node ids < 2^31 -> hi words all zero).
__global__ __launch_bounds__(256) void detect_kernel(const int* e32, int* flag) {
  __shared__ int s;
  if (threadIdx.x == 0) s = 1;
  __syncthreads();
  if (e32[2 * threadIdx.x + 1] != 0) s = 0;  // benign race, all writers write 0
  __syncthreads();
  if (threadIdx.x == 0) *flag = s;
}

__global__ __launch_bounds__(256) void hist_kernel(const void* edges, const int* flag,
                                                   int* deg, long long E) {
  long long e = (long long)blockIdx.x * 256 + threadIdx.x;
  if (e >= E) return;
  int is64 = *flag;
  int dst = edge_at(edges, is64, E + e);
  atomicAdd(&deg[dst], 1);
}

__global__ __launch_bounds__(256) void scan_reduce_kernel(const int* __restrict__ deg,
                                                          int* __restrict__ blockSums, int N) {
  __shared__ int sm[256];
  int base = blockIdx.x * 1024;
  int t = threadIdx.x;
  int s = 0;
  for (int i = t; i < 1024; i += 256) {
    int gi = base + i;
    if (gi < N) s += deg[gi];
  }
  sm[t] = s;
  __syncthreads();
  for (int o = 128; o > 0; o >>= 1) {
    if (t < o) sm[t] += sm[t + o];
    __syncthreads();
  }
  if (t == 0) blockSums[blockIdx.x] = sm[0];
}

__global__ void scan_offsets_kernel(const int* __restrict__ blockSums, int* __restrict__ blockOffs,
                                    int nb, int* __restrict__ row_ptr, int N) {
  if (threadIdx.x == 0 && blockIdx.x == 0) {
    int acc = 0;
    for (int i = 0; i < nb; ++i) { blockOffs[i] = acc; acc += blockSums[i]; }
    row_ptr[N] = acc;
  }
}

__global__ __launch_bounds__(1024) void scan_final_kernel(const int* __restrict__ deg,
                                                          const int* __restrict__ blockOffs,
                                                          int* __restrict__ row_ptr,
                                                          int* __restrict__ cursor,
                                                          float* __restrict__ deg_inv, int N) {
  __shared__ int sm[1024];
  int t = threadIdx.x;
  int gi = blockIdx.x * 1024 + t;
  int v = (gi < N) ? deg[gi] : 0;
  sm[t] = v;
  __syncthreads();
  for (int o = 1; o < 1024; o <<= 1) {
    int x = (t >= o) ? sm[t - o] : 0;
    __syncthreads();
    sm[t] += x;
    __syncthreads();
  }
  if (gi < N) {
    int excl = sm[t] - v;
    int rp = blockOffs[blockIdx.x] + excl;
    row_ptr[gi] = rp;
    cursor[gi] = rp;
    deg_inv[gi] = (v > 0) ? (1.0f / (float)v) : 0.0f;
  }
}

__global__ __launch_bounds__(256) void fill_kernel(const void* edges, const int* flag,
                                                   int* cursor, int* __restrict__ sorted_src,
                                                   long long E) {
  long long e = (long long)blockIdx.x * 256 + threadIdx.x;
  if (e >= E) return;
  int is64 = *flag;
  int src = edge_at(edges, is64, e);
  int dst = edge_at(edges, is64, E + e);
  int pos = atomicAdd(&cursor[dst], 1);
  sorted_src[pos] = src;
}

// ---------------------------------------------------------------------------
// MFMA GEMM: C[N, split+nr] = X[N,128] @ [Wl; Wr]^T, K=128 in one LDS stage.
// cols < split -> bf16 to cl[N,split]; cols >= split -> f32 to cr[N,nr].
// Tile BM=64 x BN=128, 4 waves (each 32x64 = 2x4 fragments of 16x16x32).
// LDS rows padded to 136 bf16 (272 B): ds_read_b128 hits the 8-cycle floor.
// ---------------------------------------------------------------------------
template <bool IN_BF16>
__global__ __launch_bounds__(256) void mfma_gemm_kernel(
    const void* __restrict__ Xv, const float* __restrict__ Wl, const float* __restrict__ Wr,
    u16* __restrict__ cl, float* __restrict__ cr, int N, int split, int nr) {
  __shared__ u16 As[64][136];
  __shared__ u16 Bs[128][136];
  int tid = threadIdx.x;
  int rb = blockIdx.x * 64, cb = blockIdx.y * 128;

  // stage A (X rows, convert f32->bf16 if needed)
  if (IN_BF16) {
    const u16* X = (const u16*)Xv;
    for (int i = tid; i < 64 * 16; i += 256) {
      int r = i >> 4, c8 = (i & 15) << 3;
      int gr = rb + r;
      u16x8 v = {0, 0, 0, 0, 0, 0, 0, 0};
      if (gr < N) v = *(const u16x8*)(X + (long long)gr * 128 + c8);
      *(u16x8*)&As[r][c8] = v;
    }
  } else {
    const float* X = (const float*)Xv;
    for (int i = tid; i < 64 * 32; i += 256) {
      int r = i >> 5, c4 = (i & 31) << 2;
      int gr = rb + r;
      float4 v = make_float4(0.f, 0.f, 0.f, 0.f);
      if (gr < N) v = *(const float4*)(X + (long long)gr * 128 + c4);
      u16x4 b = {f2b(v.x), f2b(v.y), f2b(v.z), f2b(v.w)};
      *(u16x4*)&As[r][c4] = b;
    }
  }
  // stage B (weight rows, f32 -> bf16)
  for (int i = tid; i < 128 * 32; i += 256) {
    int r = i >> 5, c4 = (i & 31) << 2;
    int gc = cb + r;
    const float* wrow = (gc < split) ? (Wl + (long long)gc * 128)
                                     : (Wr + (long long)(gc - split) * 128);
    float4 v = *(const float4*)(wrow + c4);
    u16x4 b = {f2b(v.x), f2b(v.y), f2b(v.z), f2b(v.w)};
    *(u16x4*)&Bs[r][c4] = b;
  }
  __syncthreads();

  int wv = tid >> 6, l = tid & 63;
  int wr = (wv & 1) * 32, wc = (wv >> 1) * 64;
  int lr = l & 15, lk = (l >> 4) * 8;

  f32x4 acc[2][4];
#pragma unroll
  for (int i = 0; i < 2; ++i)
#pragma unroll
    for (int j = 0; j < 4; ++j)
#pragma unroll
      for (int r = 0; r < 4; ++r) acc[i][j][r] = 0.f;

#pragma unroll
  for (int ks = 0; ks < 4; ++ks) {
    bf16x8 a[2], b[4];
#pragma unroll
    for (int i = 0; i < 2; ++i)
      a[i] = *(const bf16x8*)&As[wr + i * 16 + lr][ks * 32 + lk];
#pragma unroll
    for (int j = 0; j < 4; ++j)
      b[j] = *(const bf16x8*)&Bs[wc + j * 16 + lr][ks * 32 + lk];
#pragma unroll
    for (int i = 0; i < 2; ++i)
#pragma unroll
      for (int j = 0; j < 4; ++j)
        acc[i][j] = __builtin_amdgcn_mfma_f32_16x16x32_bf16(a[i], b[j], acc[i][j], 0, 0, 0);
  }

  // C/D layout (m89-verified): col = lane&15, row = (lane>>4)*4 + reg
#pragma unroll
  for (int i = 0; i < 2; ++i) {
#pragma unroll
    for (int j = 0; j < 4; ++j) {
      int gc = cb + wc + j * 16 + (l & 15);
#pragma unroll
      for (int r = 0; r < 4; ++r) {
        int gr = rb + wr + i * 16 + ((l >> 4) << 2) + r;
        if (gr < N) {
          if (gc < split) cl[(long long)gr * split + gc] = f2b(acc[i][j][r]);
          else cr[(long long)gr * nr + (gc - split)] = acc[i][j][r];
        }
      }
    }
  }
}

// Layer-1 aggregate + combine + ReLU. Wave per node, lane handles 2 channels.
__global__ __launch_bounds__(256) void agg1_kernel(const u16* __restrict__ t1l,
                                                   const float* __restrict__ t1r,
                                                   const int* __restrict__ row_ptr,
                                                   const int* __restrict__ sorted_src,
                                                   const float* __restrict__ deg_inv,
                                                   const float* __restrict__ b1,
                                                   u16* __restrict__ h, int N) {
  int node = (int)(((long long)blockIdx.x * 256 + threadIdx.x) >> 6);
  int lane = threadIdx.x & 63;
  if (node >= N) return;
  int beg = row_ptr[node], end = row_ptr[node + 1];
  float sx = 0.f, sy = 0.f;
  int e = beg;
  for (; e + 2 <= end; e += 2) {
    int s0 = sorted_src[e], s1 = sorted_src[e + 1];
    u16x2 v0 = *(const u16x2*)(t1l + (long long)s0 * 128 + lane * 2);
    u16x2 v1 = *(const u16x2*)(t1l + (long long)s1 * 128 + lane * 2);
    sx += b2f(v0[0]) + b2f(v1[0]);
    sy += b2f(v0[1]) + b2f(v1[1]);
  }
  if (e < end) {
    int s0 = sorted_src[e];
    u16x2 v0 = *(const u16x2*)(t1l + (long long)s0 * 128 + lane * 2);
    sx += b2f(v0[0]);
    sy += b2f(v0[1]);
  }
  float di = deg_inv[node];
  float2 tr = *(const float2*)(t1r + (long long)node * 128 + lane * 2);
  float2 bb = *(const float2*)(b1 + lane * 2);
  u16x2 o = {f2b(fmaxf(sx * di + tr.x + bb.x, 0.f)),
             f2b(fmaxf(sy * di + tr.y + bb.y, 0.f))};
  *(u16x2*)(h + (long long)node * 128 + lane * 2) = o;
}

// Layer-2 aggregate + combine. Wave per node, lane = channel (64 ch).
__global__ __launch_bounds__(256) void agg2_kernel(const u16* __restrict__ t3l,
                                                   const float* __restrict__ t3r,
                                                   const int* __restrict__ row_ptr,
                                                   const int* __restrict__ sorted_src,
                                                   const float* __restrict__ deg_inv,
                                                   const float* __restrict__ b2,
                                                   float* __restrict__ out, int N) {
  int node = (int)(((long long)blockIdx.x * 256 + threadIdx.x) >> 6);
  int lane = threadIdx.x & 63;
  if (node >= N) return;
  int beg = row_ptr[node], end = row_ptr[node + 1];
  float s = 0.f;
  int e = beg;
  for (; e + 2 <= end; e += 2) {
    int s0 = sorted_src[e], s1 = sorted_src[e + 1];
    s += b2f(t3l[(long long)s0 * 64 + lane]) + b2f(t3l[(long long)s1 * 64 + lane]);
  }
  if (e < end) s += b2f(t3l[(long long)sorted_src[e] * 64 + lane]);
  float r = s * deg_inv[node] + t3r[(long long)node * 64 + lane] + b2[lane];
  out[(long long)node * 64 + lane] = r;
}

extern "C" void kernel_launch(void* const* d_in, const int* in_sizes, int n_in,
                              void* d_out, int out_size, void* d_ws, size_t ws_size,
                              hipStream_t stream) {
  const float* x = (const float*)d_in[0];
  const void* edges = d_in[1];
  const float* W1l = (const float*)d_in[2];
  const float* W1r = (const float*)d_in[3];
  const float* b1 = (const float*)d_in[4];
  const float* W2l = (const float*)d_in[5];
  const float* W2r = (const float*)d_in[6];
  const float* b2 = (const float*)d_in[7];
  float* out = (float*)d_out;

  int N = in_sizes[0] / 128;
  long long E = (long long)in_sizes[1] / 2;
  int NB = (N + 1023) / 1024;

  auto align = [](size_t v) { return (v + 255) & ~(size_t)255; };
  char* ws = (char*)d_ws;
  size_t o = 0;
  int* flag = (int*)(ws + o);         o += align(sizeof(int));
  int* deg = (int*)(ws + o);          o += align((size_t)N * 4);
  int* blockSums = (int*)(ws + o);    o += align((size_t)NB * 4);
  int* blockOffs = (int*)(ws + o);    o += align((size_t)NB * 4);
  int* row_ptr = (int*)(ws + o);      o += align((size_t)(N + 1) * 4);
  int* cursor = (int*)(ws + o);       o += align((size_t)N * 4);
  float* deg_inv = (float*)(ws + o);  o += align((size_t)N * 4);
  int* sorted_src = (int*)(ws + o);   o += align((size_t)E * 4);
  u16* t1l = (u16*)(ws + o);          o += align((size_t)N * 128 * 2);
  float* t1r = (float*)(ws + o);      o += align((size_t)N * 128 * 4);
  u16* h = (u16*)(ws + o);            o += align((size_t)N * 128 * 2);
  u16* t3l = t1l;    // aliases: t1 dead once h computed
  float* t3r = t1r;

  hipMemsetAsync(deg, 0, (size_t)N * 4, stream);
  detect_kernel<<<1, 256, 0, stream>>>((const int*)edges, flag);

  int eblocks = (int)((E + 255) / 256);
  hist_kernel<<<eblocks, 256, 0, stream>>>(edges, flag, deg, E);
  scan_reduce_kernel<<<NB, 256, 0, stream>>>(deg, blockSums, N);
  scan_offsets_kernel<<<1, 64, 0, stream>>>(blockSums, blockOffs, NB, row_ptr, N);
  scan_final_kernel<<<NB, 1024, 0, stream>>>(deg, blockOffs, row_ptr, cursor, deg_inv, N);
  fill_kernel<<<eblocks, 256, 0, stream>>>(edges, flag, cursor, sorted_src, E);

  int mb = (N + 63) / 64;
  // Layer 1: [t1l | t1r] = x @ [W1_l | W1_r]^T   (split=128, nr=128)
  mfma_gemm_kernel<false><<<dim3(mb, 2), 256, 0, stream>>>(x, W1l, W1r, t1l, t1r, N, 128, 128);
  agg1_kernel<<<(N + 3) / 4, 256, 0, stream>>>(t1l, t1r, row_ptr, sorted_src, deg_inv, b1, h, N);

  // Layer 2: [t3l | t3r] = h @ [W2_l | W2_r]^T   (split=64, nr=64)
  mfma_gemm_kernel<true><<<dim3(mb, 1), 256, 0, stream>>>(h, W2l, W2r, t3l, t3r, N, 64, 64);
  agg2_kernel<<<(N + 3) / 4, 256, 0, stream>>>(t3l, t3r, row_ptr, sorted_src, deg_inv, b2, out, N);
}

// Round 3
// 306.573 us; speedup vs baseline: 2.4752x; 1.5543x over previous
//
#include <hip/hip_runtime.h>

// ---------------------------------------------------------------------------
// GraphSAGE 2-layer forward on MI355X (gfx950).
//   Layer l: out = deg_inv * segsum((x@Wl.T)[src] -> dst) + x@Wr.T + b
// GEMM-first (linearity), bf16 MFMA GEMMs with f32 accumulate.
// CSR built via two-level bucket counting sort: LDS atomics only,
// coalesced / block-local global writes (kills the 16x write amplification
// the global-atomic fill_kernel had).
// ---------------------------------------------------------------------------

typedef float f32x4 __attribute__((ext_vector_type(4)));
typedef short bf16x8 __attribute__((ext_vector_type(8)));
typedef unsigned short u16;
typedef unsigned short u16x2 __attribute__((ext_vector_type(2)));
typedef unsigned short u16x4 __attribute__((ext_vector_type(4)));
typedef unsigned short u16x8 __attribute__((ext_vector_type(8)));

#define SHIFT 9                    // nodes per bucket = 512
#define GB 128                     // blocks in count/scatter passes

__device__ __forceinline__ u16 f2b(float f) {  // f32 -> bf16 RNE (finite)
  unsigned u = __builtin_bit_cast(unsigned, f);
  u += 0x7FFFu + ((u >> 16) & 1u);
  return (u16)(u >> 16);
}
__device__ __forceinline__ float b2f(u16 s) {
  unsigned u = (unsigned)s << 16;
  return __builtin_bit_cast(float, u);
}

__device__ __forceinline__ int edge_at(const void* ep, int is64, long long idx) {
  if (is64) return (int)((const long long*)ep)[idx];
  return ((const int*)ep)[idx];
}

// int64 vs int32 edge_index detection (node ids < 2^31 -> hi words all zero).
__global__ __launch_bounds__(256) void detect_kernel(const int* e32, int* flag) {
  __shared__ int s;
  if (threadIdx.x == 0) s = 1;
  __syncthreads();
  if (e32[2 * threadIdx.x + 1] != 0) s = 0;  // benign race, all writers write 0
  __syncthreads();
  if (threadIdx.x == 0) *flag = s;
}

// Pass A: per-block bucket histogram (LDS atomics), coalesced cnt write.
__global__ __launch_bounds__(256) void countA_kernel(const void* edges, const int* flag,
                                                     int* __restrict__ cnt,
                                                     long long E, int nbuck) {
  __shared__ int h[256];
  int t = threadIdx.x;
  h[t] = 0;
  __syncthreads();
  int is64 = *flag;
  long long stride = (long long)GB * 256;
  for (long long i = (long long)blockIdx.x * 256 + t; i < E; i += stride) {
    int dst = edge_at(edges, is64, E + i);
    atomicAdd(&h[dst >> SHIFT], 1);
  }
  __syncthreads();
  if (t < nbuck) cnt[blockIdx.x * nbuck + t] = h[t];
}

// Pass B1: bucket totals + exclusive scan -> bucket_base; also row_ptr[N]=E.
__global__ __launch_bounds__(256) void scanB1_kernel(const int* __restrict__ cnt,
                                                     int* __restrict__ bucket_base,
                                                     int* __restrict__ row_ptr,
                                                     int nbuck, int N) {
  __shared__ int sm[256];
  int t = threadIdx.x;
  int total = 0;
  if (t < nbuck)
    for (int g = 0; g < GB; ++g) total += cnt[g * nbuck + t];
  sm[t] = total;
  __syncthreads();
  for (int o = 1; o < 256; o <<= 1) {
    int x = (t >= o) ? sm[t - o] : 0;
    __syncthreads();
    sm[t] += x;
    __syncthreads();
  }
  if (t < nbuck) bucket_base[t] = sm[t] - total;
  if (t == nbuck - 1) {
    bucket_base[nbuck] = sm[t];
    row_ptr[N] = sm[t];
  }
}

// Pass B2: per-(block,bucket) cursors: cur[g][b] = base[b] + prefix_g cnt[g][b].
__global__ __launch_bounds__(128) void scanB2_kernel(const int* __restrict__ cnt,
                                                     const int* __restrict__ bucket_base,
                                                     int* __restrict__ cur, int nbuck) {
  __shared__ int sm[128];
  int b = blockIdx.x, t = threadIdx.x;
  int v = cnt[t * nbuck + b];
  sm[t] = v;
  __syncthreads();
  for (int o = 1; o < 128; o <<= 1) {
    int x = (t >= o) ? sm[t - o] : 0;
    __syncthreads();
    sm[t] += x;
    __syncthreads();
  }
  cur[t * nbuck + b] = bucket_base[b] + sm[t] - v;
}

// Pass C: scatter edges into bucket-contiguous tmp arrays (LDS cursors;
// each (block,bucket) writes a contiguous ~256B run).
__global__ __launch_bounds__(256) void scatterC_kernel(const void* edges, const int* flag,
                                                       const int* __restrict__ cur,
                                                       int* __restrict__ tmps,
                                                       u16* __restrict__ tmpd,
                                                       long long E, int nbuck) {
  __shared__ int c[256];
  int t = threadIdx.x;
  if (t < nbuck) c[t] = cur[blockIdx.x * nbuck + t];
  __syncthreads();
  int is64 = *flag;
  long long stride = (long long)GB * 256;
  for (long long i = (long long)blockIdx.x * 256 + t; i < E; i += stride) {
    int src = edge_at(edges, is64, i);
    int dst = edge_at(edges, is64, E + i);
    int bk = dst >> SHIFT;
    int pos = atomicAdd(&c[bk], 1);
    tmps[pos] = src;
    tmpd[pos] = (u16)(dst & ((1 << SHIFT) - 1));
  }
}

// Pass D: per-bucket fine counting sort. Degrees + scan + scatter all in LDS;
// global writes coalesced (row_ptr/deg_inv) or block-local (sorted_src).
__global__ __launch_bounds__(512) void finesort_kernel(const int* __restrict__ tmps,
                                                       const u16* __restrict__ tmpd,
                                                       const int* __restrict__ bucket_base,
                                                       int* __restrict__ row_ptr,
                                                       float* __restrict__ deg_inv,
                                                       int* __restrict__ sorted_src, int N) {
  __shared__ int dg[512];
  __shared__ int sm[512];
  int b = blockIdx.x, t = threadIdx.x;
  int s = bucket_base[b], e = bucket_base[b + 1];
  dg[t] = 0;
  __syncthreads();
  for (int i = s + t; i < e; i += 512) atomicAdd(&dg[tmpd[i]], 1);
  __syncthreads();
  int v = dg[t];
  sm[t] = v;
  __syncthreads();
  for (int o = 1; o < 512; o <<= 1) {
    int x = (t >= o) ? sm[t - o] : 0;
    __syncthreads();
    sm[t] += x;
    __syncthreads();
  }
  int excl = sm[t] - v;
  int node = (b << SHIFT) + t;
  if (node < N) {
    row_ptr[node] = s + excl;
    deg_inv[node] = (v > 0) ? (1.0f / (float)v) : 0.0f;
  }
  sm[t] = s + excl;  // own cell only: becomes the scatter cursor
  __syncthreads();
  for (int i = s + t; i < e; i += 512) {
    int l = tmpd[i];
    int pos = atomicAdd(&sm[l], 1);
    sorted_src[pos] = tmps[i];
  }
}

// ---------------------------------------------------------------------------
// MFMA GEMM: C[N, split+nr] = X[N,128] @ [Wl; Wr]^T, K=128 in one LDS stage.
// cols < split -> bf16 to cl; cols >= split -> f32 to cr.
// ---------------------------------------------------------------------------
template <bool IN_BF16>
__global__ __launch_bounds__(256) void mfma_gemm_kernel(
    const void* __restrict__ Xv, const float* __restrict__ Wl, const float* __restrict__ Wr,
    u16* __restrict__ cl, float* __restrict__ cr, int N, int split, int nr) {
  __shared__ u16 As[64][136];
  __shared__ u16 Bs[128][136];
  int tid = threadIdx.x;
  int rb = blockIdx.x * 64, cb = blockIdx.y * 128;

  if (IN_BF16) {
    const u16* X = (const u16*)Xv;
    for (int i = tid; i < 64 * 16; i += 256) {
      int r = i >> 4, c8 = (i & 15) << 3;
      int gr = rb + r;
      u16x8 v = {0, 0, 0, 0, 0, 0, 0, 0};
      if (gr < N) v = *(const u16x8*)(X + (long long)gr * 128 + c8);
      *(u16x8*)&As[r][c8] = v;
    }
  } else {
    const float* X = (const float*)Xv;
    for (int i = tid; i < 64 * 32; i += 256) {
      int r = i >> 5, c4 = (i & 31) << 2;
      int gr = rb + r;
      float4 v = make_float4(0.f, 0.f, 0.f, 0.f);
      if (gr < N) v = *(const float4*)(X + (long long)gr * 128 + c4);
      u16x4 bb = {f2b(v.x), f2b(v.y), f2b(v.z), f2b(v.w)};
      *(u16x4*)&As[r][c4] = bb;
    }
  }
  for (int i = tid; i < 128 * 32; i += 256) {
    int r = i >> 5, c4 = (i & 31) << 2;
    int gc = cb + r;
    const float* wrow = (gc < split) ? (Wl + (long long)gc * 128)
                                     : (Wr + (long long)(gc - split) * 128);
    float4 v = *(const float4*)(wrow + c4);
    u16x4 bb = {f2b(v.x), f2b(v.y), f2b(v.z), f2b(v.w)};
    *(u16x4*)&Bs[r][c4] = bb;
  }
  __syncthreads();

  int wv = tid >> 6, l = tid & 63;
  int wr = (wv & 1) * 32, wc = (wv >> 1) * 64;
  int lr = l & 15, lk = (l >> 4) * 8;

  f32x4 acc[2][4];
#pragma unroll
  for (int i = 0; i < 2; ++i)
#pragma unroll
    for (int j = 0; j < 4; ++j)
#pragma unroll
      for (int r = 0; r < 4; ++r) acc[i][j][r] = 0.f;

#pragma unroll
  for (int ks = 0; ks < 4; ++ks) {
    bf16x8 a[2], b[4];
#pragma unroll
    for (int i = 0; i < 2; ++i)
      a[i] = *(const bf16x8*)&As[wr + i * 16 + lr][ks * 32 + lk];
#pragma unroll
    for (int j = 0; j < 4; ++j)
      b[j] = *(const bf16x8*)&Bs[wc + j * 16 + lr][ks * 32 + lk];
#pragma unroll
    for (int i = 0; i < 2; ++i)
#pragma unroll
      for (int j = 0; j < 4; ++j)
        acc[i][j] = __builtin_amdgcn_mfma_f32_16x16x32_bf16(a[i], b[j], acc[i][j], 0, 0, 0);
  }

  // C/D layout: col = lane&15, row = (lane>>4)*4 + reg
#pragma unroll
  for (int i = 0; i < 2; ++i) {
#pragma unroll
    for (int j = 0; j < 4; ++j) {
      int gc = cb + wc + j * 16 + (l & 15);
#pragma unroll
      for (int r = 0; r < 4; ++r) {
        int gr = rb + wr + i * 16 + ((l >> 4) << 2) + r;
        if (gr < N) {
          if (gc < split) cl[(long long)gr * split + gc] = f2b(acc[i][j][r]);
          else cr[(long long)gr * nr + (gc - split)] = acc[i][j][r];
        }
      }
    }
  }
}

// Layer-1 aggregate + combine + ReLU. Wave per node, lane handles 2 channels.
__global__ __launch_bounds__(256) void agg1_kernel(const u16* __restrict__ t1l,
                                                   const float* __restrict__ t1r,
                                                   const int* __restrict__ row_ptr,
                                                   const int* __restrict__ sorted_src,
                                                   const float* __restrict__ deg_inv,
                                                   const float* __restrict__ b1,
                                                   u16* __restrict__ h, int N) {
  int node = (int)(((long long)blockIdx.x * 256 + threadIdx.x) >> 6);
  int lane = threadIdx.x & 63;
  if (node >= N) return;
  int beg = row_ptr[node], end = row_ptr[node + 1];
  float sx = 0.f, sy = 0.f;
  int e = beg;
  for (; e + 4 <= end; e += 4) {
    int s0 = sorted_src[e], s1 = sorted_src[e + 1];
    int s2 = sorted_src[e + 2], s3 = sorted_src[e + 3];
    u16x2 v0 = *(const u16x2*)(t1l + (long long)s0 * 128 + lane * 2);
    u16x2 v1 = *(const u16x2*)(t1l + (long long)s1 * 128 + lane * 2);
    u16x2 v2 = *(const u16x2*)(t1l + (long long)s2 * 128 + lane * 2);
    u16x2 v3 = *(const u16x2*)(t1l + (long long)s3 * 128 + lane * 2);
    sx += b2f(v0[0]) + b2f(v1[0]) + b2f(v2[0]) + b2f(v3[0]);
    sy += b2f(v0[1]) + b2f(v1[1]) + b2f(v2[1]) + b2f(v3[1]);
  }
  for (; e < end; ++e) {
    int s0 = sorted_src[e];
    u16x2 v0 = *(const u16x2*)(t1l + (long long)s0 * 128 + lane * 2);
    sx += b2f(v0[0]);
    sy += b2f(v0[1]);
  }
  float di = deg_inv[node];
  float2 tr = *(const float2*)(t1r + (long long)node * 128 + lane * 2);
  float2 bb = *(const float2*)(b1 + lane * 2);
  u16x2 o = {f2b(fmaxf(sx * di + tr.x + bb.x, 0.f)),
             f2b(fmaxf(sy * di + tr.y + bb.y, 0.f))};
  *(u16x2*)(h + (long long)node * 128 + lane * 2) = o;
}

// Layer-2 aggregate + combine. Wave per node, lane = channel (64 ch).
__global__ __launch_bounds__(256) void agg2_kernel(const u16* __restrict__ t3l,
                                                   const float* __restrict__ t3r,
                                                   const int* __restrict__ row_ptr,
                                                   const int* __restrict__ sorted_src,
                                                   const float* __restrict__ deg_inv,
                                                   const float* __restrict__ b2,
                                                   float* __restrict__ out, int N) {
  int node = (int)(((long long)blockIdx.x * 256 + threadIdx.x) >> 6);
  int lane = threadIdx.x & 63;
  if (node >= N) return;
  int beg = row_ptr[node], end = row_ptr[node + 1];
  float s = 0.f;
  int e = beg;
  for (; e + 4 <= end; e += 4) {
    int s0 = sorted_src[e], s1 = sorted_src[e + 1];
    int s2 = sorted_src[e + 2], s3 = sorted_src[e + 3];
    s += b2f(t3l[(long long)s0 * 64 + lane]) + b2f(t3l[(long long)s1 * 64 + lane]) +
         b2f(t3l[(long long)s2 * 64 + lane]) + b2f(t3l[(long long)s3 * 64 + lane]);
  }
  for (; e < end; ++e) s += b2f(t3l[(long long)sorted_src[e] * 64 + lane]);
  float r = s * deg_inv[node] + t3r[(long long)node * 64 + lane] + b2[lane];
  out[(long long)node * 64 + lane] = r;
}

extern "C" void kernel_launch(void* const* d_in, const int* in_sizes, int n_in,
                              void* d_out, int out_size, void* d_ws, size_t ws_size,
                              hipStream_t stream) {
  const float* x = (const float*)d_in[0];
  const void* edges = d_in[1];
  const float* W1l = (const float*)d_in[2];
  const float* W1r = (const float*)d_in[3];
  const float* b1 = (const float*)d_in[4];
  const float* W2l = (const float*)d_in[5];
  const float* W2r = (const float*)d_in[6];
  const float* b2 = (const float*)d_in[7];
  float* out = (float*)d_out;

  int N = in_sizes[0] / 128;
  long long E = (long long)in_sizes[1] / 2;
  int nbuck = (N + (1 << SHIFT) - 1) >> SHIFT;  // 196 for N=100000 (<=256 required)

  auto align = [](size_t v) { return (v + 255) & ~(size_t)255; };
  char* ws = (char*)d_ws;
  size_t o = 0;
  int* flag = (int*)(ws + o);         o += align(sizeof(int));
  int* bucket_base = (int*)(ws + o);  o += align((size_t)(nbuck + 1) * 4);
  int* cnt = (int*)(ws + o);          o += align((size_t)GB * nbuck * 4);
  int* cur = (int*)(ws + o);          o += align((size_t)GB * nbuck * 4);
  int* row_ptr = (int*)(ws + o);      o += align((size_t)(N + 1) * 4);
  float* deg_inv = (float*)(ws + o);  o += align((size_t)N * 4);
  int* sorted_src = (int*)(ws + o);   o += align((size_t)E * 4);
  int* tmps = (int*)(ws + o);         o += align((size_t)E * 4);
  u16* tmpd = (u16*)(ws + o);         o += align((size_t)E * 2);
  u16* t1l = (u16*)(ws + o);          o += align((size_t)N * 128 * 2);
  float* t1r = (float*)(ws + o);      o += align((size_t)N * 128 * 4);
  u16* h = (u16*)(ws + o);            o += align((size_t)N * 128 * 2);
  u16* t3l = t1l;    // aliases: t1 dead once h computed
  float* t3r = t1r;

  detect_kernel<<<1, 256, 0, stream>>>((const int*)edges, flag);
  countA_kernel<<<GB, 256, 0, stream>>>(edges, flag, cnt, E, nbuck);
  scanB1_kernel<<<1, 256, 0, stream>>>(cnt, bucket_base, row_ptr, nbuck, N);
  scanB2_kernel<<<nbuck, 128, 0, stream>>>(cnt, bucket_base, cur, nbuck);
  scatterC_kernel<<<GB, 256, 0, stream>>>(edges, flag, cur, tmps, tmpd, E, nbuck);
  finesort_kernel<<<nbuck, 512, 0, stream>>>(tmps, tmpd, bucket_base, row_ptr, deg_inv,
                                             sorted_src, N);

  int mb = (N + 63) / 64;
  // Layer 1: [t1l | t1r] = x @ [W1_l | W1_r]^T   (split=128, nr=128)
  mfma_gemm_kernel<false><<<dim3(mb, 2), 256, 0, stream>>>(x, W1l, W1r, t1l, t1r, N, 128, 128);
  agg1_kernel<<<(N + 3) / 4, 256, 0, stream>>>(t1l, t1r, row_ptr, sorted_src, deg_inv, b1, h, N);

  // Layer 2: [t3l | t3r] = h @ [W2_l | W2_r]^T   (split=64, nr=64)
  mfma_gemm_kernel<true><<<dim3(mb, 1), 256, 0, stream>>>(h, W2l, W2r, t3l, t3r, N, 64, 64);
  agg2_kernel<<<(N + 3) / 4, 256, 0, stream>>>(t3l, t3r, row_ptr, sorted_src, deg_inv, b2, out, N);
}

// Round 4
// 253.285 us; speedup vs baseline: 2.9959x; 1.2104x over previous
//
#include <hip/hip_runtime.h>

// ---------------------------------------------------------------------------
// GraphSAGE 2-layer forward on MI355X (gfx950).
//   Layer l: out = deg_inv * segsum((x@Wl.T)[src] -> dst) + x@Wr.T + b
// GEMM-first (linearity). bf16 MFMA GEMM: stage weights once per block,
// loop over M-tiles with double-buffered A and lgkm-only barriers (prefetch
// loads stay in flight across the barrier - no vmcnt(0) drain in main loop).
// CSR via two-level LDS-atomic bucket sort. All intermediates bf16.
// ---------------------------------------------------------------------------

typedef float f32x4 __attribute__((ext_vector_type(4)));
typedef short bf16x8 __attribute__((ext_vector_type(8)));
typedef unsigned short u16;
typedef unsigned short u16x2 __attribute__((ext_vector_type(2)));
typedef unsigned short u16x4 __attribute__((ext_vector_type(4)));
typedef unsigned short u16x8 __attribute__((ext_vector_type(8)));

#define SHIFT 9                    // nodes per bucket = 512
#define GB 256                     // blocks in count/scatter passes

__device__ __forceinline__ u16 f2b(float f) {  // f32 -> bf16 RNE (finite)
  unsigned u = __builtin_bit_cast(unsigned, f);
  u += 0x7FFFu + ((u >> 16) & 1u);
  return (u16)(u >> 16);
}
__device__ __forceinline__ float b2f(u16 s) {
  unsigned u = (unsigned)s << 16;
  return __builtin_bit_cast(float, u);
}

__device__ __forceinline__ int edge_at(const void* ep, int is64, long long idx) {
  if (is64) return (int)((const long long*)ep)[idx];
  return ((const int*)ep)[idx];
}

// int64 vs int32 edge_index detection (node ids < 2^31 -> hi words all zero).
__global__ __launch_bounds__(256) void detect_kernel(const int* e32, int* flag) {
  __shared__ int s;
  if (threadIdx.x == 0) s = 1;
  __syncthreads();
  if (e32[2 * threadIdx.x + 1] != 0) s = 0;  // benign race, all writers write 0
  __syncthreads();
  if (threadIdx.x == 0) *flag = s;
}

// Pass A: per-block bucket histogram (LDS atomics), coalesced cnt write.
__global__ __launch_bounds__(256) void countA_kernel(const void* edges, const int* flag,
                                                     int* __restrict__ cnt,
                                                     long long E, int nbuck) {
  __shared__ int h[256];
  int t = threadIdx.x;
  h[t] = 0;
  __syncthreads();
  int is64 = *flag;
  long long stride = (long long)GB * 256;
  for (long long i = (long long)blockIdx.x * 256 + t; i < E; i += stride) {
    int dst = edge_at(edges, is64, E + i);
    atomicAdd(&h[dst >> SHIFT], 1);
  }
  __syncthreads();
  if (t < nbuck) cnt[blockIdx.x * nbuck + t] = h[t];
}

// Pass B1: bucket totals + exclusive scan -> bucket_base; also row_ptr[N]=E.
__global__ __launch_bounds__(256) void scanB1_kernel(const int* __restrict__ cnt,
                                                     int* __restrict__ bucket_base,
                                                     int* __restrict__ row_ptr,
                                                     int nbuck, int N) {
  __shared__ int sm[256];
  int t = threadIdx.x;
  int total = 0;
  if (t < nbuck)
    for (int g = 0; g < GB; ++g) total += cnt[g * nbuck + t];
  sm[t] = total;
  __syncthreads();
  for (int o = 1; o < 256; o <<= 1) {
    int x = (t >= o) ? sm[t - o] : 0;
    __syncthreads();
    sm[t] += x;
    __syncthreads();
  }
  if (t < nbuck) bucket_base[t] = sm[t] - total;
  if (t == nbuck - 1) {
    bucket_base[nbuck] = sm[t];
    row_ptr[N] = sm[t];
  }
}

// Pass B2: per-(block,bucket) cursors: cur[g][b] = base[b] + prefix_g cnt[g][b].
__global__ __launch_bounds__(256) void scanB2_kernel(const int* __restrict__ cnt,
                                                     const int* __restrict__ bucket_base,
                                                     int* __restrict__ cur, int nbuck) {
  __shared__ int sm[256];
  int b = blockIdx.x, t = threadIdx.x;
  int v = cnt[t * nbuck + b];
  sm[t] = v;
  __syncthreads();
  for (int o = 1; o < 256; o <<= 1) {
    int x = (t >= o) ? sm[t - o] : 0;
    __syncthreads();
    sm[t] += x;
    __syncthreads();
  }
  cur[t * nbuck + b] = bucket_base[b] + sm[t] - v;
}

// Pass C: scatter edges into bucket-contiguous tmp arrays (LDS cursors).
__global__ __launch_bounds__(256) void scatterC_kernel(const void* edges, const int* flag,
                                                       const int* __restrict__ cur,
                                                       int* __restrict__ tmps,
                                                       u16* __restrict__ tmpd,
                                                       long long E, int nbuck) {
  __shared__ int c[256];
  int t = threadIdx.x;
  if (t < nbuck) c[t] = cur[blockIdx.x * nbuck + t];
  __syncthreads();
  int is64 = *flag;
  long long stride = (long long)GB * 256;
  for (long long i = (long long)blockIdx.x * 256 + t; i < E; i += stride) {
    int src = edge_at(edges, is64, i);
    int dst = edge_at(edges, is64, E + i);
    int bk = dst >> SHIFT;
    int pos = atomicAdd(&c[bk], 1);
    tmps[pos] = src;
    tmpd[pos] = (u16)(dst & ((1 << SHIFT) - 1));
  }
}

// Pass D: per-bucket fine counting sort, all cursors in LDS.
__global__ __launch_bounds__(512) void finesort_kernel(const int* __restrict__ tmps,
                                                       const u16* __restrict__ tmpd,
                                                       const int* __restrict__ bucket_base,
                                                       int* __restrict__ row_ptr,
                                                       float* __restrict__ deg_inv,
                                                       int* __restrict__ sorted_src, int N) {
  __shared__ int dg[512];
  __shared__ int sm[512];
  int b = blockIdx.x, t = threadIdx.x;
  int s = bucket_base[b], e = bucket_base[b + 1];
  dg[t] = 0;
  __syncthreads();
  for (int i = s + t; i < e; i += 512) atomicAdd(&dg[tmpd[i]], 1);
  __syncthreads();
  int v = dg[t];
  sm[t] = v;
  __syncthreads();
  for (int o = 1; o < 512; o <<= 1) {
    int x = (t >= o) ? sm[t - o] : 0;
    __syncthreads();
    sm[t] += x;
    __syncthreads();
  }
  int excl = sm[t] - v;
  int node = (b << SHIFT) + t;
  if (node < N) {
    row_ptr[node] = s + excl;
    deg_inv[node] = (v > 0) ? (1.0f / (float)v) : 0.0f;
  }
  sm[t] = s + excl;  // own cell only: becomes the scatter cursor
  __syncthreads();
  for (int i = s + t; i < e; i += 512) {
    int l = tmpd[i];
    int pos = atomicAdd(&sm[l], 1);
    sorted_src[pos] = tmps[i];
  }
}

// ---------------------------------------------------------------------------
// MFMA GEMM, stage-B-once + M-loop: C[:, split+nr] = X[N,128] @ [Wl; Wr]^T.
// 128 output cols per block (blockIdx.y tile). Double-buffered A, one
// lgkm-drained raw barrier per iteration (A prefetch + C stores stay in
// flight under MFMA). Both output halves bf16.
// ---------------------------------------------------------------------------
template <bool IN_BF16>
__global__ __launch_bounds__(256) void gemm_loop_kernel(
    const void* __restrict__ Xv, const float* __restrict__ Wl, const float* __restrict__ Wr,
    u16* __restrict__ cl, u16* __restrict__ cr, int N, int split, int nr, int mtiles) {
  __shared__ u16 Bs[128][136];
  __shared__ u16 As[2][64][136];
  int tid = threadIdx.x;
  int cb = blockIdx.y * 128;

  const float* Xf = (const float*)Xv;
  const u16* Xb = (const u16*)Xv;
  float4 af[8];
  u16x8 ab[4];

  auto loadA = [&](int mt) {
    long long rb = (long long)mt * 64;
    if constexpr (IN_BF16) {
#pragma unroll
      for (int k = 0; k < 4; ++k) {
        int i = tid + (k << 8);
        int r = i >> 4, c8 = (i & 15) << 3;
        long long gr = rb + r;
        if (gr >= N) gr = N - 1;
        ab[k] = *(const u16x8*)(Xb + gr * 128 + c8);
      }
    } else {
#pragma unroll
      for (int k = 0; k < 8; ++k) {
        int i = tid + (k << 8);
        int r = i >> 5, c4 = (i & 31) << 2;
        long long gr = rb + r;
        if (gr >= N) gr = N - 1;
        af[k] = *(const float4*)(Xf + gr * 128 + c4);
      }
    }
  };
  auto writeA = [&](int buf) {
    if constexpr (IN_BF16) {
#pragma unroll
      for (int k = 0; k < 4; ++k) {
        int i = tid + (k << 8);
        int r = i >> 4, c8 = (i & 15) << 3;
        *(u16x8*)&As[buf][r][c8] = ab[k];
      }
    } else {
#pragma unroll
      for (int k = 0; k < 8; ++k) {
        int i = tid + (k << 8);
        int r = i >> 5, c4 = (i & 31) << 2;
        u16x4 bb = {f2b(af[k].x), f2b(af[k].y), f2b(af[k].z), f2b(af[k].w)};
        *(u16x4*)&As[buf][r][c4] = bb;
      }
    }
  };

  if (blockIdx.x < mtiles) loadA(blockIdx.x);

  // stage B once (weights; L2-resident, every block same y reads same rows)
  for (int i = tid; i < 128 * 32; i += 256) {
    int r = i >> 5, c4 = (i & 31) << 2;
    int gc = cb + r;
    const float* wrow = (gc < split) ? (Wl + (long long)gc * 128)
                                     : (Wr + (long long)(gc - split) * 128);
    float4 v = *(const float4*)(wrow + c4);
    u16x4 bb = {f2b(v.x), f2b(v.y), f2b(v.z), f2b(v.w)};
    *(u16x4*)&Bs[r][c4] = bb;
  }

  int wv = tid >> 6, l = tid & 63;
  int wr = (wv & 1) * 32, wc = (wv >> 1) * 64;
  int lr = l & 15, lk = (l >> 4) * 8;

  int lt = 0;
  for (int mt = blockIdx.x; mt < mtiles; mt += gridDim.x, ++lt) {
    int buf = lt & 1;
    writeA(buf);                       // consume prefetch regs -> LDS
    int nmt = mt + gridDim.x;
    if (nmt < mtiles) loadA(nmt);      // issue next loads; in flight across barrier
    asm volatile("s_waitcnt lgkmcnt(0)" ::: "memory");  // ds_writes visible
    __builtin_amdgcn_s_barrier();      // NO vmcnt drain: prefetch stays in flight

    f32x4 acc[2][4];
#pragma unroll
    for (int i = 0; i < 2; ++i)
#pragma unroll
      for (int j = 0; j < 4; ++j)
#pragma unroll
        for (int r = 0; r < 4; ++r) acc[i][j][r] = 0.f;

#pragma unroll
    for (int ks = 0; ks < 4; ++ks) {
      bf16x8 a[2], b[4];
#pragma unroll
      for (int i = 0; i < 2; ++i)
        a[i] = *(const bf16x8*)&As[buf][wr + i * 16 + lr][ks * 32 + lk];
#pragma unroll
      for (int j = 0; j < 4; ++j)
        b[j] = *(const bf16x8*)&Bs[wc + j * 16 + lr][ks * 32 + lk];
#pragma unroll
      for (int i = 0; i < 2; ++i)
#pragma unroll
        for (int j = 0; j < 4; ++j)
          acc[i][j] = __builtin_amdgcn_mfma_f32_16x16x32_bf16(a[i], b[j], acc[i][j], 0, 0, 0);
    }

    // C/D layout: col = lane&15, row = (lane>>4)*4 + reg
    long long rb = (long long)mt * 64;
#pragma unroll
    for (int i = 0; i < 2; ++i) {
#pragma unroll
      for (int j = 0; j < 4; ++j) {
        int gc = cb + wc + j * 16 + (l & 15);
#pragma unroll
        for (int r = 0; r < 4; ++r) {
          long long gr = rb + wr + i * 16 + ((l >> 4) << 2) + r;
          if (gr < N) {
            if (gc < split) cl[gr * split + gc] = f2b(acc[i][j][r]);
            else cr[gr * nr + (gc - split)] = f2b(acc[i][j][r]);
          }
        }
      }
    }
    // next iter writes the OTHER A buffer; barrier above (next iter) protects
    // this buffer's readers before overwrite two iters from now.
  }
}

// Layer-1 aggregate + combine + ReLU. Wave per node, lane handles 2 channels.
__global__ __launch_bounds__(256) void agg1_kernel(const u16* __restrict__ t1l,
                                                   const u16* __restrict__ t1r,
                                                   const int* __restrict__ row_ptr,
                                                   const int* __restrict__ sorted_src,
                                                   const float* __restrict__ deg_inv,
                                                   const float* __restrict__ b1,
                                                   u16* __restrict__ h, int N) {
  int node = (int)(((long long)blockIdx.x * 256 + threadIdx.x) >> 6);
  int lane = threadIdx.x & 63;
  if (node >= N) return;
  int beg = row_ptr[node], end = row_ptr[node + 1];
  float sx = 0.f, sy = 0.f;
  int e = beg;
  for (; e + 4 <= end; e += 4) {
    int s0 = sorted_src[e], s1 = sorted_src[e + 1];
    int s2 = sorted_src[e + 2], s3 = sorted_src[e + 3];
    u16x2 v0 = *(const u16x2*)(t1l + (long long)s0 * 128 + lane * 2);
    u16x2 v1 = *(const u16x2*)(t1l + (long long)s1 * 128 + lane * 2);
    u16x2 v2 = *(const u16x2*)(t1l + (long long)s2 * 128 + lane * 2);
    u16x2 v3 = *(const u16x2*)(t1l + (long long)s3 * 128 + lane * 2);
    sx += b2f(v0[0]) + b2f(v1[0]) + b2f(v2[0]) + b2f(v3[0]);
    sy += b2f(v0[1]) + b2f(v1[1]) + b2f(v2[1]) + b2f(v3[1]);
  }
  for (; e < end; ++e) {
    int s0 = sorted_src[e];
    u16x2 v0 = *(const u16x2*)(t1l + (long long)s0 * 128 + lane * 2);
    sx += b2f(v0[0]);
    sy += b2f(v0[1]);
  }
  float di = deg_inv[node];
  u16x2 trb = *(const u16x2*)(t1r + (long long)node * 128 + lane * 2);
  float2 bb = *(const float2*)(b1 + lane * 2);
  u16x2 o = {f2b(fmaxf(sx * di + b2f(trb[0]) + bb.x, 0.f)),
             f2b(fmaxf(sy * di + b2f(trb[1]) + bb.y, 0.f))};
  *(u16x2*)(h + (long long)node * 128 + lane * 2) = o;
}

// Layer-2 aggregate + combine. Wave per node, lane = channel (64 ch).
__global__ __launch_bounds__(256) void agg2_kernel(const u16* __restrict__ t3l,
                                                   const u16* __restrict__ t3r,
                                                   const int* __restrict__ row_ptr,
                                                   const int* __restrict__ sorted_src,
                                                   const float* __restrict__ deg_inv,
                                                   const float* __restrict__ b2,
                                                   float* __restrict__ out, int N) {
  int node = (int)(((long long)blockIdx.x * 256 + threadIdx.x) >> 6);
  int lane = threadIdx.x & 63;
  if (node >= N) return;
  int beg = row_ptr[node], end = row_ptr[node + 1];
  float s = 0.f;
  int e = beg;
  for (; e + 4 <= end; e += 4) {
    int s0 = sorted_src[e], s1 = sorted_src[e + 1];
    int s2 = sorted_src[e + 2], s3 = sorted_src[e + 3];
    s += b2f(t3l[(long long)s0 * 64 + lane]) + b2f(t3l[(long long)s1 * 64 + lane]) +
         b2f(t3l[(long long)s2 * 64 + lane]) + b2f(t3l[(long long)s3 * 64 + lane]);
  }
  for (; e < end; ++e) s += b2f(t3l[(long long)sorted_src[e] * 64 + lane]);
  float r = s * deg_inv[node] + b2f(t3r[(long long)node * 64 + lane]) + b2[lane];
  out[(long long)node * 64 + lane] = r;
}

extern "C" void kernel_launch(void* const* d_in, const int* in_sizes, int n_in,
                              void* d_out, int out_size, void* d_ws, size_t ws_size,
                              hipStream_t stream) {
  const float* x = (const float*)d_in[0];
  const void* edges = d_in[1];
  const float* W1l = (const float*)d_in[2];
  const float* W1r = (const float*)d_in[3];
  const float* b1 = (const float*)d_in[4];
  const float* W2l = (const float*)d_in[5];
  const float* W2r = (const float*)d_in[6];
  const float* b2 = (const float*)d_in[7];
  float* out = (float*)d_out;

  int N = in_sizes[0] / 128;
  long long E = (long long)in_sizes[1] / 2;
  int nbuck = (N + (1 << SHIFT) - 1) >> SHIFT;  // 196 for N=100000 (<=256 required)

  auto align = [](size_t v) { return (v + 255) & ~(size_t)255; };
  char* ws = (char*)d_ws;
  size_t o = 0;
  int* flag = (int*)(ws + o);         o += align(sizeof(int));
  int* bucket_base = (int*)(ws + o);  o += align((size_t)(nbuck + 1) * 4);
  int* cnt = (int*)(ws + o);          o += align((size_t)GB * nbuck * 4);
  int* cur = (int*)(ws + o);          o += align((size_t)GB * nbuck * 4);
  int* row_ptr = (int*)(ws + o);      o += align((size_t)(N + 1) * 4);
  float* deg_inv = (float*)(ws + o);  o += align((size_t)N * 4);
  int* sorted_src = (int*)(ws + o);   o += align((size_t)E * 4);
  int* tmps = (int*)(ws + o);         o += align((size_t)E * 4);
  u16* tmpd = (u16*)(ws + o);         o += align((size_t)E * 2);
  u16* t1l = (u16*)(ws + o);          o += align((size_t)N * 128 * 2);
  u16* t1r = (u16*)(ws + o);          o += align((size_t)N * 128 * 2);
  u16* h = (u16*)(ws + o);            o += align((size_t)N * 128 * 2);
  u16* t3l = t1l;    // aliases: t1 dead once h computed
  u16* t3r = t1r;

  detect_kernel<<<1, 256, 0, stream>>>((const int*)edges, flag);
  countA_kernel<<<GB, 256, 0, stream>>>(edges, flag, cnt, E, nbuck);
  scanB1_kernel<<<1, 256, 0, stream>>>(cnt, bucket_base, row_ptr, nbuck, N);
  scanB2_kernel<<<nbuck, 256, 0, stream>>>(cnt, bucket_base, cur, nbuck);
  scatterC_kernel<<<GB, 256, 0, stream>>>(edges, flag, cur, tmps, tmpd, E, nbuck);
  finesort_kernel<<<nbuck, 512, 0, stream>>>(tmps, tmpd, bucket_base, row_ptr, deg_inv,
                                             sorted_src, N);

  int mb = (N + 63) / 64;
  // Layer 1: [t1l | t1r] = x @ [W1_l | W1_r]^T  (split=128, nr=128, 2 col-tiles)
  gemm_loop_kernel<false><<<dim3(256, 2), 256, 0, stream>>>(x, W1l, W1r, t1l, t1r, N, 128, 128, mb);
  agg1_kernel<<<(N + 3) / 4, 256, 0, stream>>>(t1l, t1r, row_ptr, sorted_src, deg_inv, b1, h, N);

  // Layer 2: [t3l | t3r] = h @ [W2_l | W2_r]^T  (split=64, nr=64, 1 col-tile)
  gemm_loop_kernel<true><<<dim3(512, 1), 256, 0, stream>>>(h, W2l, W2r, t3l, t3r, N, 64, 64, mb);
  agg2_kernel<<<(N + 3) / 4, 256, 0, stream>>>(t3l, t3r, row_ptr, sorted_src, deg_inv, b2, out, N);
}

// Round 5
// 222.586 us; speedup vs baseline: 3.4091x; 1.1379x over previous
//
#include <hip/hip_runtime.h>

// ---------------------------------------------------------------------------
// GraphSAGE 2-layer forward on MI355X (gfx950).
//   Layer l: out = deg_inv * segsum((x@Wl.T)[src] -> dst) + x@Wr.T + b
// GEMM-first (linearity). bf16 MFMA GEMM with stage-B-once + M-loop and
// lgkm-only barriers. CSR via two-level LDS-atomic bucket sort.
// Aggregation: multi-edge-per-instruction gathers (32-lane rows for 256B,
// 16-lane rows for 128B) to maximize memory-level parallelism.
// ---------------------------------------------------------------------------

typedef float f32x4 __attribute__((ext_vector_type(4)));
typedef short bf16x8 __attribute__((ext_vector_type(8)));
typedef unsigned short u16;
typedef unsigned short u16x2 __attribute__((ext_vector_type(2)));
typedef unsigned short u16x4 __attribute__((ext_vector_type(4)));
typedef unsigned short u16x8 __attribute__((ext_vector_type(8)));

#define SHIFT 9                    // nodes per bucket = 512
#define GB 256                     // blocks in count/scatter passes

__device__ __forceinline__ u16 f2b(float f) {  // f32 -> bf16 RNE (finite)
  unsigned u = __builtin_bit_cast(unsigned, f);
  u += 0x7FFFu + ((u >> 16) & 1u);
  return (u16)(u >> 16);
}
__device__ __forceinline__ float b2f(u16 s) {
  unsigned u = (unsigned)s << 16;
  return __builtin_bit_cast(float, u);
}

__device__ __forceinline__ int edge_at(const void* ep, int is64, long long idx) {
  if (is64) return (int)((const long long*)ep)[idx];
  return ((const int*)ep)[idx];
}

// Per-block int64-vs-int32 detection: sample hi words of first 256 entries.
// int32 srcs are random nonzero (P(all 256 zero) ~ 1e-1280); int64 hi = 0.
__device__ __forceinline__ int detect64(const void* edges, int* sflag) {
  int t = threadIdx.x;
  if (t == 0) *sflag = 1;
  __syncthreads();
  if (t < 256 && ((const int*)edges)[2 * t + 1] != 0) *sflag = 0;  // benign race
  __syncthreads();
  return *sflag;
}

// Pass A: per-block bucket histogram (LDS atomics), coalesced cnt write.
__global__ __launch_bounds__(256) void countA_kernel(const void* edges,
                                                     int* __restrict__ cnt,
                                                     long long E, int nbuck) {
  __shared__ int h[256];
  __shared__ int sflag;
  int is64 = detect64(edges, &sflag);
  int t = threadIdx.x;
  h[t] = 0;
  __syncthreads();
  long long stride = (long long)GB * 256;
  for (long long i = (long long)blockIdx.x * 256 + t; i < E; i += stride) {
    int dst = edge_at(edges, is64, E + i);
    atomicAdd(&h[dst >> SHIFT], 1);
  }
  __syncthreads();
  if (t < nbuck) cnt[blockIdx.x * nbuck + t] = h[t];
}

// Pass B1: bucket totals + exclusive scan -> bucket_base; also row_ptr[N]=E.
__global__ __launch_bounds__(256) void scanB1_kernel(const int* __restrict__ cnt,
                                                     int* __restrict__ bucket_base,
                                                     int* __restrict__ row_ptr,
                                                     int nbuck, int N) {
  __shared__ int sm[256];
  int t = threadIdx.x;
  int total = 0;
  if (t < nbuck)
    for (int g = 0; g < GB; ++g) total += cnt[g * nbuck + t];
  sm[t] = total;
  __syncthreads();
  for (int o = 1; o < 256; o <<= 1) {
    int x = (t >= o) ? sm[t - o] : 0;
    __syncthreads();
    sm[t] += x;
    __syncthreads();
  }
  if (t < nbuck) bucket_base[t] = sm[t] - total;
  if (t == nbuck - 1) {
    bucket_base[nbuck] = sm[t];
    row_ptr[N] = sm[t];
  }
}

// Pass B2: per-(block,bucket) cursors: cur[g][b] = base[b] + prefix_g cnt[g][b].
__global__ __launch_bounds__(256) void scanB2_kernel(const int* __restrict__ cnt,
                                                     const int* __restrict__ bucket_base,
                                                     int* __restrict__ cur, int nbuck) {
  __shared__ int sm[256];
  int b = blockIdx.x, t = threadIdx.x;
  int v = cnt[t * nbuck + b];
  sm[t] = v;
  __syncthreads();
  for (int o = 1; o < 256; o <<= 1) {
    int x = (t >= o) ? sm[t - o] : 0;
    __syncthreads();
    sm[t] += x;
    __syncthreads();
  }
  cur[t * nbuck + b] = bucket_base[b] + sm[t] - v;
}

// Pass C: scatter edges into bucket-contiguous tmp arrays (LDS cursors).
__global__ __launch_bounds__(256) void scatterC_kernel(const void* edges,
                                                       const int* __restrict__ cur,
                                                       int* __restrict__ tmps,
                                                       u16* __restrict__ tmpd,
                                                       long long E, int nbuck) {
  __shared__ int c[256];
  __shared__ int sflag;
  int is64 = detect64(edges, &sflag);
  int t = threadIdx.x;
  if (t < nbuck) c[t] = cur[blockIdx.x * nbuck + t];
  __syncthreads();
  long long stride = (long long)GB * 256;
  for (long long i = (long long)blockIdx.x * 256 + t; i < E; i += stride) {
    int src = edge_at(edges, is64, i);
    int dst = edge_at(edges, is64, E + i);
    int bk = dst >> SHIFT;
    int pos = atomicAdd(&c[bk], 1);
    tmps[pos] = src;
    tmpd[pos] = (u16)(dst & ((1 << SHIFT) - 1));
  }
}

// Pass D: per-bucket fine counting sort, all cursors in LDS.
__global__ __launch_bounds__(512) void finesort_kernel(const int* __restrict__ tmps,
                                                       const u16* __restrict__ tmpd,
                                                       const int* __restrict__ bucket_base,
                                                       int* __restrict__ row_ptr,
                                                       float* __restrict__ deg_inv,
                                                       int* __restrict__ sorted_src, int N) {
  __shared__ int dg[512];
  __shared__ int sm[512];
  int b = blockIdx.x, t = threadIdx.x;
  int s = bucket_base[b], e = bucket_base[b + 1];
  dg[t] = 0;
  __syncthreads();
  for (int i = s + t; i < e; i += 512) atomicAdd(&dg[tmpd[i]], 1);
  __syncthreads();
  int v = dg[t];
  sm[t] = v;
  __syncthreads();
  for (int o = 1; o < 512; o <<= 1) {
    int x = (t >= o) ? sm[t - o] : 0;
    __syncthreads();
    sm[t] += x;
    __syncthreads();
  }
  int excl = sm[t] - v;
  int node = (b << SHIFT) + t;
  if (node < N) {
    row_ptr[node] = s + excl;
    deg_inv[node] = (v > 0) ? (1.0f / (float)v) : 0.0f;
  }
  sm[t] = s + excl;  // own cell only: becomes the scatter cursor
  __syncthreads();
  for (int i = s + t; i < e; i += 512) {
    int l = tmpd[i];
    int pos = atomicAdd(&sm[l], 1);
    sorted_src[pos] = tmps[i];
  }
}

// ---------------------------------------------------------------------------
// MFMA GEMM, stage-B-once + M-loop, double-buffered A, lgkm-only barrier.
// ---------------------------------------------------------------------------
template <bool IN_BF16>
__global__ __launch_bounds__(256) void gemm_loop_kernel(
    const void* __restrict__ Xv, const float* __restrict__ Wl, const float* __restrict__ Wr,
    u16* __restrict__ cl, u16* __restrict__ cr, int N, int split, int nr, int mtiles) {
  __shared__ u16 Bs[128][136];
  __shared__ u16 As[2][64][136];
  int tid = threadIdx.x;
  int cb = blockIdx.y * 128;

  const float* Xf = (const float*)Xv;
  const u16* Xb = (const u16*)Xv;
  float4 af[8];
  u16x8 ab[4];

  auto loadA = [&](int mt) {
    long long rb = (long long)mt * 64;
    if constexpr (IN_BF16) {
#pragma unroll
      for (int k = 0; k < 4; ++k) {
        int i = tid + (k << 8);
        int r = i >> 4, c8 = (i & 15) << 3;
        long long gr = rb + r;
        if (gr >= N) gr = N - 1;
        ab[k] = *(const u16x8*)(Xb + gr * 128 + c8);
      }
    } else {
#pragma unroll
      for (int k = 0; k < 8; ++k) {
        int i = tid + (k << 8);
        int r = i >> 5, c4 = (i & 31) << 2;
        long long gr = rb + r;
        if (gr >= N) gr = N - 1;
        af[k] = *(const float4*)(Xf + gr * 128 + c4);
      }
    }
  };
  auto writeA = [&](int buf) {
    if constexpr (IN_BF16) {
#pragma unroll
      for (int k = 0; k < 4; ++k) {
        int i = tid + (k << 8);
        int r = i >> 4, c8 = (i & 15) << 3;
        *(u16x8*)&As[buf][r][c8] = ab[k];
      }
    } else {
#pragma unroll
      for (int k = 0; k < 8; ++k) {
        int i = tid + (k << 8);
        int r = i >> 5, c4 = (i & 31) << 2;
        u16x4 bb = {f2b(af[k].x), f2b(af[k].y), f2b(af[k].z), f2b(af[k].w)};
        *(u16x4*)&As[buf][r][c4] = bb;
      }
    }
  };

  if (blockIdx.x < mtiles) loadA(blockIdx.x);

  // stage B once (weights; L2-resident)
  for (int i = tid; i < 128 * 32; i += 256) {
    int r = i >> 5, c4 = (i & 31) << 2;
    int gc = cb + r;
    const float* wrow = (gc < split) ? (Wl + (long long)gc * 128)
                                     : (Wr + (long long)(gc - split) * 128);
    float4 v = *(const float4*)(wrow + c4);
    u16x4 bb = {f2b(v.x), f2b(v.y), f2b(v.z), f2b(v.w)};
    *(u16x4*)&Bs[r][c4] = bb;
  }

  int wv = tid >> 6, l = tid & 63;
  int wr = (wv & 1) * 32, wc = (wv >> 1) * 64;
  int lr = l & 15, lk = (l >> 4) * 8;

  int lt = 0;
  for (int mt = blockIdx.x; mt < mtiles; mt += gridDim.x, ++lt) {
    int buf = lt & 1;
    writeA(buf);                       // consume prefetch regs -> LDS
    int nmt = mt + gridDim.x;
    if (nmt < mtiles) loadA(nmt);      // next loads stay in flight across barrier
    asm volatile("s_waitcnt lgkmcnt(0)" ::: "memory");  // ds_writes visible
    __builtin_amdgcn_s_barrier();      // NO vmcnt drain

    f32x4 acc[2][4];
#pragma unroll
    for (int i = 0; i < 2; ++i)
#pragma unroll
      for (int j = 0; j < 4; ++j)
#pragma unroll
        for (int r = 0; r < 4; ++r) acc[i][j][r] = 0.f;

#pragma unroll
    for (int ks = 0; ks < 4; ++ks) {
      bf16x8 a[2], b[4];
#pragma unroll
      for (int i = 0; i < 2; ++i)
        a[i] = *(const bf16x8*)&As[buf][wr + i * 16 + lr][ks * 32 + lk];
#pragma unroll
      for (int j = 0; j < 4; ++j)
        b[j] = *(const bf16x8*)&Bs[wc + j * 16 + lr][ks * 32 + lk];
#pragma unroll
      for (int i = 0; i < 2; ++i)
#pragma unroll
        for (int j = 0; j < 4; ++j)
          acc[i][j] = __builtin_amdgcn_mfma_f32_16x16x32_bf16(a[i], b[j], acc[i][j], 0, 0, 0);
    }

    // C/D layout: col = lane&15, row = (lane>>4)*4 + reg
    long long rb = (long long)mt * 64;
#pragma unroll
    for (int i = 0; i < 2; ++i) {
#pragma unroll
      for (int j = 0; j < 4; ++j) {
        int gc = cb + wc + j * 16 + (l & 15);
#pragma unroll
        for (int r = 0; r < 4; ++r) {
          long long gr = rb + wr + i * 16 + ((l >> 4) << 2) + r;
          if (gr < N) {
            if (gc < split) cl[gr * split + gc] = f2b(acc[i][j][r]);
            else cr[gr * nr + (gc - split)] = f2b(acc[i][j][r]);
          }
        }
      }
    }
  }
}

// Layer-1 aggregate + combine + ReLU. Wave per node; 32-lane halves each
// gather a full 256B row (u16x4/lane) -> 2 edges per VMEM instr, unroll 4.
__global__ __launch_bounds__(256) void agg1_kernel(const u16* __restrict__ t1l,
                                                   const u16* __restrict__ t1r,
                                                   const int* __restrict__ row_ptr,
                                                   const int* __restrict__ sorted_src,
                                                   const float* __restrict__ deg_inv,
                                                   const float* __restrict__ b1,
                                                   u16* __restrict__ h, int N) {
  int node = (int)(((long long)blockIdx.x * 256 + threadIdx.x) >> 6);
  int lane = threadIdx.x & 63;
  if (node >= N) return;
  int beg = row_ptr[node], end = row_ptr[node + 1];
  int half = lane >> 5;
  int ci = lane & 31;  // channels ci*4 .. ci*4+3

  // hoist self-path loads (overlap with gathers)
  float di = deg_inv[node];
  u16x4 tr = *(const u16x4*)(t1r + (long long)node * 128 + ci * 4);
  f32x4 bb = *(const f32x4*)(b1 + ci * 4);

  f32x4 acc = {0.f, 0.f, 0.f, 0.f};
  int e = beg + half;
  for (; e + 6 < end; e += 8) {  // 4 pairs: 8 edges in flight per wave
    int s0 = sorted_src[e], s1 = sorted_src[e + 2];
    int s2 = sorted_src[e + 4], s3 = sorted_src[e + 6];
    u16x4 v0 = *(const u16x4*)(t1l + (long long)s0 * 128 + ci * 4);
    u16x4 v1 = *(const u16x4*)(t1l + (long long)s1 * 128 + ci * 4);
    u16x4 v2 = *(const u16x4*)(t1l + (long long)s2 * 128 + ci * 4);
    u16x4 v3 = *(const u16x4*)(t1l + (long long)s3 * 128 + ci * 4);
#pragma unroll
    for (int k = 0; k < 4; ++k)
      acc[k] += (b2f(v0[k]) + b2f(v1[k])) + (b2f(v2[k]) + b2f(v3[k]));
  }
  for (; e < end; e += 2) {
    int s0 = sorted_src[e];
    u16x4 v0 = *(const u16x4*)(t1l + (long long)s0 * 128 + ci * 4);
#pragma unroll
    for (int k = 0; k < 4; ++k) acc[k] += b2f(v0[k]);
  }
#pragma unroll
  for (int k = 0; k < 4; ++k) acc[k] += __shfl_xor(acc[k], 32);
  if (half == 0) {
    u16x4 o;
#pragma unroll
    for (int k = 0; k < 4; ++k)
      o[k] = f2b(fmaxf(acc[k] * di + b2f(tr[k]) + bb[k], 0.f));
    *(u16x4*)(h + (long long)node * 128 + ci * 4) = o;
  }
}

// Layer-2 aggregate + combine. Wave per node; 16-lane quarters each gather a
// full 128B row (u16x4/lane) -> 4 edges per VMEM instr, unroll 2.
__global__ __launch_bounds__(256) void agg2_kernel(const u16* __restrict__ t3l,
                                                   const u16* __restrict__ t3r,
                                                   const int* __restrict__ row_ptr,
                                                   const int* __restrict__ sorted_src,
                                                   const float* __restrict__ deg_inv,
                                                   const float* __restrict__ b2,
                                                   float* __restrict__ out, int N) {
  int node = (int)(((long long)blockIdx.x * 256 + threadIdx.x) >> 6);
  int lane = threadIdx.x & 63;
  if (node >= N) return;
  int beg = row_ptr[node], end = row_ptr[node + 1];
  int q = lane >> 4;
  int ci = lane & 15;  // channels ci*4 .. ci*4+3

  float di = deg_inv[node];
  u16x4 tr = *(const u16x4*)(t3r + (long long)node * 64 + ci * 4);
  f32x4 bb = *(const f32x4*)(b2 + ci * 4);

  f32x4 acc = {0.f, 0.f, 0.f, 0.f};
  int e = beg + q;
  for (; e + 4 < end; e += 8) {  // 2 quads: 8 edges in flight per wave
    int s0 = sorted_src[e], s1 = sorted_src[e + 4];
    u16x4 v0 = *(const u16x4*)(t3l + (long long)s0 * 64 + ci * 4);
    u16x4 v1 = *(const u16x4*)(t3l + (long long)s1 * 64 + ci * 4);
#pragma unroll
    for (int k = 0; k < 4; ++k) acc[k] += b2f(v0[k]) + b2f(v1[k]);
  }
  for (; e < end; e += 4) {
    int s0 = sorted_src[e];
    u16x4 v0 = *(const u16x4*)(t3l + (long long)s0 * 64 + ci * 4);
#pragma unroll
    for (int k = 0; k < 4; ++k) acc[k] += b2f(v0[k]);
  }
#pragma unroll
  for (int k = 0; k < 4; ++k) {
    acc[k] += __shfl_xor(acc[k], 16);
    acc[k] += __shfl_xor(acc[k], 32);
  }
  if (q == 0) {
    f32x4 o;
#pragma unroll
    for (int k = 0; k < 4; ++k) o[k] = acc[k] * di + b2f(tr[k]) + bb[k];
    *(f32x4*)(out + (long long)node * 64 + ci * 4) = o;
  }
}

extern "C" void kernel_launch(void* const* d_in, const int* in_sizes, int n_in,
                              void* d_out, int out_size, void* d_ws, size_t ws_size,
                              hipStream_t stream) {
  const float* x = (const float*)d_in[0];
  const void* edges = d_in[1];
  const float* W1l = (const float*)d_in[2];
  const float* W1r = (const float*)d_in[3];
  const float* b1 = (const float*)d_in[4];
  const float* W2l = (const float*)d_in[5];
  const float* W2r = (const float*)d_in[6];
  const float* b2 = (const float*)d_in[7];
  float* out = (float*)d_out;

  int N = in_sizes[0] / 128;
  long long E = (long long)in_sizes[1] / 2;
  int nbuck = (N + (1 << SHIFT) - 1) >> SHIFT;  // 196 for N=100000 (<=256 required)

  auto align = [](size_t v) { return (v + 255) & ~(size_t)255; };
  char* ws = (char*)d_ws;
  size_t o = 0;
  int* bucket_base = (int*)(ws + o);  o += align((size_t)(nbuck + 1) * 4);
  int* cnt = (int*)(ws + o);          o += align((size_t)GB * nbuck * 4);
  int* cur = (int*)(ws + o);          o += align((size_t)GB * nbuck * 4);
  int* row_ptr = (int*)(ws + o);      o += align((size_t)(N + 1) * 4);
  float* deg_inv = (float*)(ws + o);  o += align((size_t)N * 4);
  int* sorted_src = (int*)(ws + o);   o += align((size_t)E * 4);
  int* tmps = (int*)(ws + o);         o += align((size_t)E * 4);
  u16* tmpd = (u16*)(ws + o);         o += align((size_t)E * 2);
  u16* t1l = (u16*)(ws + o);          o += align((size_t)N * 128 * 2);
  u16* t1r = (u16*)(ws + o);          o += align((size_t)N * 128 * 2);
  u16* h = (u16*)(ws + o);            o += align((size_t)N * 128 * 2);
  u16* t3l = t1l;    // aliases: t1 dead once h computed
  u16* t3r = t1r;

  countA_kernel<<<GB, 256, 0, stream>>>(edges, cnt, E, nbuck);
  scanB1_kernel<<<1, 256, 0, stream>>>(cnt, bucket_base, row_ptr, nbuck, N);
  scanB2_kernel<<<nbuck, 256, 0, stream>>>(cnt, bucket_base, cur, nbuck);
  scatterC_kernel<<<GB, 256, 0, stream>>>(edges, cur, tmps, tmpd, E, nbuck);
  finesort_kernel<<<nbuck, 512, 0, stream>>>(tmps, tmpd, bucket_base, row_ptr, deg_inv,
                                             sorted_src, N);

  int mb = (N + 63) / 64;
  // Layer 1: [t1l | t1r] = x @ [W1_l | W1_r]^T  (split=128, nr=128, 2 col-tiles)
  gemm_loop_kernel<false><<<dim3(256, 2), 256, 0, stream>>>(x, W1l, W1r, t1l, t1r, N, 128, 128, mb);
  agg1_kernel<<<(N + 3) / 4, 256, 0, stream>>>(t1l, t1r, row_ptr, sorted_src, deg_inv, b1, h, N);

  // Layer 2: [t3l | t3r] = h @ [W2_l | W2_r]^T  (split=64, nr=64, 1 col-tile)
  gemm_loop_kernel<true><<<dim3(512, 1), 256, 0, stream>>>(h, W2l, W2r, t3l, t3r, N, 64, 64, mb);
  agg2_kernel<<<(N + 3) / 4, 256, 0, stream>>>(t3l, t3r, row_ptr, sorted_src, deg_inv, b2, out, N);
}

// Round 7
// 213.729 us; speedup vs baseline: 3.5504x; 1.0414x over previous
//
#include <hip/hip_runtime.h>

// ---------------------------------------------------------------------------
// GraphSAGE 2-layer forward on MI355X (gfx950).
//   Layer l: out = deg_inv * segsum((x@Wl.T)[src] -> dst) + x@Wr.T + b
// GEMM-first (linearity). bf16 MFMA GEMM (stage-B-once + M-loop, lgkm-only
// barriers). CSR via two-level LDS-atomic bucket sort.
// Gathered tables (t1l/t3l) stored fp8-e4m3 (HW cvt) -> halves random-gather
// bytes and shrinks the table toward L2 capacity. Self paths stay bf16.
// ---------------------------------------------------------------------------

typedef float f32x2 __attribute__((ext_vector_type(2)));
typedef float f32x4 __attribute__((ext_vector_type(4)));
typedef short bf16x8 __attribute__((ext_vector_type(8)));
typedef unsigned short u16;
typedef unsigned char u8;
typedef unsigned short u16x4 __attribute__((ext_vector_type(4)));
typedef unsigned short u16x8 __attribute__((ext_vector_type(8)));

#define SHIFT 9                    // nodes per bucket = 512
#define GB 256                     // blocks in count/scatter passes

__device__ __forceinline__ u16 f2b(float f) {  // f32 -> bf16 RNE (finite)
  unsigned u = __builtin_bit_cast(unsigned, f);
  u += 0x7FFFu + ((u >> 16) & 1u);
  return (u16)(u >> 16);
}
__device__ __forceinline__ float b2f(u16 s) {
  unsigned u = (unsigned)s << 16;
  return __builtin_bit_cast(float, u);
}
__device__ __forceinline__ u8 f2fp8(float f) {  // f32 -> fp8 e4m3 (HW, RNE)
  int p = __builtin_amdgcn_cvt_pk_fp8_f32(f, f, 0, false);
  return (u8)(p & 0xFF);
}
// decode 4 packed fp8 (one dword) -> 4 f32; word-selects are literal consts
__device__ __forceinline__ f32x4 fp8x4_to_f32x4(int w) {
  f32x2 lo = __builtin_amdgcn_cvt_pk_f32_fp8(w, 0);
  f32x2 hi = __builtin_amdgcn_cvt_pk_f32_fp8(w, 1);
  f32x4 r = {lo[0], lo[1], hi[0], hi[1]};
  return r;
}

__device__ __forceinline__ int edge_at(const void* ep, int is64, long long idx) {
  if (is64) return (int)((const long long*)ep)[idx];
  return ((const int*)ep)[idx];
}

// Per-block int64-vs-int32 detection: sample hi words of first 256 entries.
__device__ __forceinline__ int detect64(const void* edges, int* sflag) {
  int t = threadIdx.x;
  if (t == 0) *sflag = 1;
  __syncthreads();
  if (t < 256 && ((const int*)edges)[2 * t + 1] != 0) *sflag = 0;  // benign race
  __syncthreads();
  return *sflag;
}

// Pass A: per-block bucket histogram (LDS atomics), coalesced cnt write.
__global__ __launch_bounds__(256) void countA_kernel(const void* edges,
                                                     int* __restrict__ cnt,
                                                     long long E, int nbuck) {
  __shared__ int h[256];
  __shared__ int sflag;
  int is64 = detect64(edges, &sflag);
  int t = threadIdx.x;
  h[t] = 0;
  __syncthreads();
  long long stride = (long long)GB * 256;
  for (long long i = (long long)blockIdx.x * 256 + t; i < E; i += stride) {
    int dst = edge_at(edges, is64, E + i);
    atomicAdd(&h[dst >> SHIFT], 1);
  }
  __syncthreads();
  if (t < nbuck) cnt[blockIdx.x * nbuck + t] = h[t];
}

// Pass B1: bucket totals + exclusive scan -> bucket_base; also row_ptr[N]=E.
__global__ __launch_bounds__(256) void scanB1_kernel(const int* __restrict__ cnt,
                                                     int* __restrict__ bucket_base,
                                                     int* __restrict__ row_ptr,
                                                     int nbuck, int N) {
  __shared__ int sm[256];
  int t = threadIdx.x;
  int total = 0;
  if (t < nbuck)
    for (int g = 0; g < GB; ++g) total += cnt[g * nbuck + t];
  sm[t] = total;
  __syncthreads();
  for (int o = 1; o < 256; o <<= 1) {
    int x = (t >= o) ? sm[t - o] : 0;
    __syncthreads();
    sm[t] += x;
    __syncthreads();
  }
  if (t < nbuck) bucket_base[t] = sm[t] - total;
  if (t == nbuck - 1) {
    bucket_base[nbuck] = sm[t];
    row_ptr[N] = sm[t];
  }
}

// Pass B2: per-(block,bucket) cursors: cur[g][b] = base[b] + prefix_g cnt[g][b].
__global__ __launch_bounds__(256) void scanB2_kernel(const int* __restrict__ cnt,
                                                     const int* __restrict__ bucket_base,
                                                     int* __restrict__ cur, int nbuck) {
  __shared__ int sm[256];
  int b = blockIdx.x, t = threadIdx.x;
  int v = cnt[t * nbuck + b];
  sm[t] = v;
  __syncthreads();
  for (int o = 1; o < 256; o <<= 1) {
    int x = (t >= o) ? sm[t - o] : 0;
    __syncthreads();
    sm[t] += x;
    __syncthreads();
  }
  cur[t * nbuck + b] = bucket_base[b] + sm[t] - v;
}

// Pass C: scatter edges into bucket-contiguous tmp arrays (LDS cursors).
__global__ __launch_bounds__(256) void scatterC_kernel(const void* edges,
                                                       const int* __restrict__ cur,
                                                       int* __restrict__ tmps,
                                                       u16* __restrict__ tmpd,
                                                       long long E, int nbuck) {
  __shared__ int c[256];
  __shared__ int sflag;
  int is64 = detect64(edges, &sflag);
  int t = threadIdx.x;
  if (t < nbuck) c[t] = cur[blockIdx.x * nbuck + t];
  __syncthreads();
  long long stride = (long long)GB * 256;
  for (long long i = (long long)blockIdx.x * 256 + t; i < E; i += stride) {
    int src = edge_at(edges, is64, i);
    int dst = edge_at(edges, is64, E + i);
    int bk = dst >> SHIFT;
    int pos = atomicAdd(&c[bk], 1);
    tmps[pos] = src;
    tmpd[pos] = (u16)(dst & ((1 << SHIFT) - 1));
  }
}

// Pass D: per-bucket fine counting sort, all cursors in LDS.
__global__ __launch_bounds__(512) void finesort_kernel(const int* __restrict__ tmps,
                                                       const u16* __restrict__ tmpd,
                                                       const int* __restrict__ bucket_base,
                                                       int* __restrict__ row_ptr,
                                                       float* __restrict__ deg_inv,
                                                       int* __restrict__ sorted_src, int N) {
  __shared__ int dg[512];
  __shared__ int sm[512];
  int b = blockIdx.x, t = threadIdx.x;
  int s = bucket_base[b], e = bucket_base[b + 1];
  dg[t] = 0;
  __syncthreads();
  for (int i = s + t; i < e; i += 512) atomicAdd(&dg[tmpd[i]], 1);
  __syncthreads();
  int v = dg[t];
  sm[t] = v;
  __syncthreads();
  for (int o = 1; o < 512; o <<= 1) {
    int x = (t >= o) ? sm[t - o] : 0;
    __syncthreads();
    sm[t] += x;
    __syncthreads();
  }
  int excl = sm[t] - v;
  int node = (b << SHIFT) + t;
  if (node < N) {
    row_ptr[node] = s + excl;
    deg_inv[node] = (v > 0) ? (1.0f / (float)v) : 0.0f;
  }
  sm[t] = s + excl;  // own cell only: becomes the scatter cursor
  __syncthreads();
  for (int i = s + t; i < e; i += 512) {
    int l = tmpd[i];
    int pos = atomicAdd(&sm[l], 1);
    sorted_src[pos] = tmps[i];
  }
}

// ---------------------------------------------------------------------------
// MFMA GEMM, stage-B-once + M-loop, double-buffered A, lgkm-only barrier.
// Gathered-half cols (< split) stored fp8; self-half cols stored bf16.
// ---------------------------------------------------------------------------
template <bool IN_BF16>
__global__ __launch_bounds__(256) void gemm_loop_kernel(
    const void* __restrict__ Xv, const float* __restrict__ Wl, const float* __restrict__ Wr,
    u8* __restrict__ cl, u16* __restrict__ cr, int N, int split, int nr, int mtiles) {
  __shared__ u16 Bs[128][136];
  __shared__ u16 As[2][64][136];
  int tid = threadIdx.x;
  int cb = blockIdx.y * 128;

  const float* Xf = (const float*)Xv;
  const u16* Xb = (const u16*)Xv;
  float4 af[8];
  u16x8 ab[4];

  auto loadA = [&](int mt) {
    long long rb = (long long)mt * 64;
    if constexpr (IN_BF16) {
#pragma unroll
      for (int k = 0; k < 4; ++k) {
        int i = tid + (k << 8);
        int r = i >> 4, c8 = (i & 15) << 3;
        long long gr = rb + r;
        if (gr >= N) gr = N - 1;
        ab[k] = *(const u16x8*)(Xb + gr * 128 + c8);
      }
    } else {
#pragma unroll
      for (int k = 0; k < 8; ++k) {
        int i = tid + (k << 8);
        int r = i >> 5, c4 = (i & 31) << 2;
        long long gr = rb + r;
        if (gr >= N) gr = N - 1;
        af[k] = *(const float4*)(Xf + gr * 128 + c4);
      }
    }
  };
  auto writeA = [&](int buf) {
    if constexpr (IN_BF16) {
#pragma unroll
      for (int k = 0; k < 4; ++k) {
        int i = tid + (k << 8);
        int r = i >> 4, c8 = (i & 15) << 3;
        *(u16x8*)&As[buf][r][c8] = ab[k];
      }
    } else {
#pragma unroll
      for (int k = 0; k < 8; ++k) {
        int i = tid + (k << 8);
        int r = i >> 5, c4 = (i & 31) << 2;
        u16x4 bb = {f2b(af[k].x), f2b(af[k].y), f2b(af[k].z), f2b(af[k].w)};
        *(u16x4*)&As[buf][r][c4] = bb;
      }
    }
  };

  if (blockIdx.x < mtiles) loadA(blockIdx.x);

  // stage B once (weights; L2-resident)
  for (int i = tid; i < 128 * 32; i += 256) {
    int r = i >> 5, c4 = (i & 31) << 2;
    int gc = cb + r;
    const float* wrow = (gc < split) ? (Wl + (long long)gc * 128)
                                     : (Wr + (long long)(gc - split) * 128);
    float4 v = *(const float4*)(wrow + c4);
    u16x4 bb = {f2b(v.x), f2b(v.y), f2b(v.z), f2b(v.w)};
    *(u16x4*)&Bs[r][c4] = bb;
  }

  int wv = tid >> 6, l = tid & 63;
  int wr = (wv & 1) * 32, wc = (wv >> 1) * 64;
  int lr = l & 15, lk = (l >> 4) * 8;

  int lt = 0;
  for (int mt = blockIdx.x; mt < mtiles; mt += gridDim.x, ++lt) {
    int buf = lt & 1;
    writeA(buf);                       // consume prefetch regs -> LDS
    int nmt = mt + gridDim.x;
    if (nmt < mtiles) loadA(nmt);      // next loads stay in flight across barrier
    asm volatile("s_waitcnt lgkmcnt(0)" ::: "memory");  // ds_writes visible
    __builtin_amdgcn_s_barrier();      // NO vmcnt drain

    f32x4 acc[2][4];
#pragma unroll
    for (int i = 0; i < 2; ++i)
#pragma unroll
      for (int j = 0; j < 4; ++j)
#pragma unroll
        for (int r = 0; r < 4; ++r) acc[i][j][r] = 0.f;

#pragma unroll
    for (int ks = 0; ks < 4; ++ks) {
      bf16x8 a[2], b[4];
#pragma unroll
      for (int i = 0; i < 2; ++i)
        a[i] = *(const bf16x8*)&As[buf][wr + i * 16 + lr][ks * 32 + lk];
#pragma unroll
      for (int j = 0; j < 4; ++j)
        b[j] = *(const bf16x8*)&Bs[wc + j * 16 + lr][ks * 32 + lk];
#pragma unroll
      for (int i = 0; i < 2; ++i)
#pragma unroll
        for (int j = 0; j < 4; ++j)
          acc[i][j] = __builtin_amdgcn_mfma_f32_16x16x32_bf16(a[i], b[j], acc[i][j], 0, 0, 0);
    }

    // C/D layout: col = lane&15, row = (lane>>4)*4 + reg
    long long rb = (long long)mt * 64;
#pragma unroll
    for (int i = 0; i < 2; ++i) {
#pragma unroll
      for (int j = 0; j < 4; ++j) {
        int gc = cb + wc + j * 16 + (l & 15);
#pragma unroll
        for (int r = 0; r < 4; ++r) {
          long long gr = rb + wr + i * 16 + ((l >> 4) << 2) + r;
          if (gr < N) {
            if (gc < split) cl[gr * split + gc] = f2fp8(acc[i][j][r]);
            else cr[gr * nr + (gc - split)] = f2b(acc[i][j][r]);
          }
        }
      }
    }
  }
}

// Layer-1 aggregate + combine + ReLU. Wave per node; 32-lane halves each
// gather a full 128B fp8 row (int/lane = 4ch) -> 2 edges per VMEM instr.
__global__ __launch_bounds__(256) void agg1_kernel(const u8* __restrict__ t1l,
                                                   const u16* __restrict__ t1r,
                                                   const int* __restrict__ row_ptr,
                                                   const int* __restrict__ sorted_src,
                                                   const float* __restrict__ deg_inv,
                                                   const float* __restrict__ b1,
                                                   u16* __restrict__ h, int N) {
  int node = (int)(((long long)blockIdx.x * 256 + threadIdx.x) >> 6);
  int lane = threadIdx.x & 63;
  if (node >= N) return;
  int beg = row_ptr[node], end = row_ptr[node + 1];
  int half = lane >> 5;
  int ci = lane & 31;  // channels ci*4 .. ci*4+3

  float di = deg_inv[node];
  u16x4 tr = *(const u16x4*)(t1r + (long long)node * 128 + ci * 4);
  f32x4 bb = *(const f32x4*)(b1 + ci * 4);

  f32x4 acc = {0.f, 0.f, 0.f, 0.f};
  int e = beg + half;
  for (; e + 6 < end; e += 8) {  // 4 pairs: 8 edges in flight per wave
    int s0 = sorted_src[e], s1 = sorted_src[e + 2];
    int s2 = sorted_src[e + 4], s3 = sorted_src[e + 6];
    int w0 = *(const int*)(t1l + (long long)s0 * 128 + ci * 4);
    int w1 = *(const int*)(t1l + (long long)s1 * 128 + ci * 4);
    int w2 = *(const int*)(t1l + (long long)s2 * 128 + ci * 4);
    int w3 = *(const int*)(t1l + (long long)s3 * 128 + ci * 4);
    f32x4 d0 = fp8x4_to_f32x4(w0);
    f32x4 d1 = fp8x4_to_f32x4(w1);
    f32x4 d2 = fp8x4_to_f32x4(w2);
    f32x4 d3 = fp8x4_to_f32x4(w3);
#pragma unroll
    for (int k = 0; k < 4; ++k)
      acc[k] += (d0[k] + d1[k]) + (d2[k] + d3[k]);
  }
  for (; e < end; e += 2) {
    int s0 = sorted_src[e];
    int w0 = *(const int*)(t1l + (long long)s0 * 128 + ci * 4);
    f32x4 d0 = fp8x4_to_f32x4(w0);
#pragma unroll
    for (int k = 0; k < 4; ++k) acc[k] += d0[k];
  }
#pragma unroll
  for (int k = 0; k < 4; ++k) acc[k] += __shfl_xor(acc[k], 32);
  if (half == 0) {
    u16x4 o;
#pragma unroll
    for (int k = 0; k < 4; ++k)
      o[k] = f2b(fmaxf(acc[k] * di + b2f(tr[k]) + bb[k], 0.f));
    *(u16x4*)(h + (long long)node * 128 + ci * 4) = o;
  }
}

// Layer-2 aggregate + combine. Wave per node; 16-lane quarters each gather a
// full 64B fp8 row (int/lane = 4ch) -> 4 edges per VMEM instr.
__global__ __launch_bounds__(256) void agg2_kernel(const u8* __restrict__ t3l,
                                                   const u16* __restrict__ t3r,
                                                   const int* __restrict__ row_ptr,
                                                   const int* __restrict__ sorted_src,
                                                   const float* __restrict__ deg_inv,
                                                   const float* __restrict__ b2,
                                                   float* __restrict__ out, int N) {
  int node = (int)(((long long)blockIdx.x * 256 + threadIdx.x) >> 6);
  int lane = threadIdx.x & 63;
  if (node >= N) return;
  int beg = row_ptr[node], end = row_ptr[node + 1];
  int q = lane >> 4;
  int ci = lane & 15;  // channels ci*4 .. ci*4+3

  float di = deg_inv[node];
  u16x4 tr = *(const u16x4*)(t3r + (long long)node * 64 + ci * 4);
  f32x4 bb = *(const f32x4*)(b2 + ci * 4);

  f32x4 acc = {0.f, 0.f, 0.f, 0.f};
  int e = beg + q;
  for (; e + 4 < end; e += 8) {  // 2 quads: 8 edges in flight per wave
    int s0 = sorted_src[e], s1 = sorted_src[e + 4];
    int w0 = *(const int*)(t3l + (long long)s0 * 64 + ci * 4);
    int w1 = *(const int*)(t3l + (long long)s1 * 64 + ci * 4);
    f32x4 d0 = fp8x4_to_f32x4(w0);
    f32x4 d1 = fp8x4_to_f32x4(w1);
#pragma unroll
    for (int k = 0; k < 4; ++k) acc[k] += d0[k] + d1[k];
  }
  for (; e < end; e += 4) {
    int s0 = sorted_src[e];
    int w0 = *(const int*)(t3l + (long long)s0 * 64 + ci * 4);
    f32x4 d0 = fp8x4_to_f32x4(w0);
#pragma unroll
    for (int k = 0; k < 4; ++k) acc[k] += d0[k];
  }
#pragma unroll
  for (int k = 0; k < 4; ++k) {
    acc[k] += __shfl_xor(acc[k], 16);
    acc[k] += __shfl_xor(acc[k], 32);
  }
  if (q == 0) {
    f32x4 o;
#pragma unroll
    for (int k = 0; k < 4; ++k) o[k] = acc[k] * di + b2f(tr[k]) + bb[k];
    *(f32x4*)(out + (long long)node * 64 + ci * 4) = o;
  }
}

extern "C" void kernel_launch(void* const* d_in, const int* in_sizes, int n_in,
                              void* d_out, int out_size, void* d_ws, size_t ws_size,
                              hipStream_t stream) {
  const float* x = (const float*)d_in[0];
  const void* edges = d_in[1];
  const float* W1l = (const float*)d_in[2];
  const float* W1r = (const float*)d_in[3];
  const float* b1 = (const float*)d_in[4];
  const float* W2l = (const float*)d_in[5];
  const float* W2r = (const float*)d_in[6];
  const float* b2 = (const float*)d_in[7];
  float* out = (float*)d_out;

  int N = in_sizes[0] / 128;
  long long E = (long long)in_sizes[1] / 2;
  int nbuck = (N + (1 << SHIFT) - 1) >> SHIFT;  // 196 for N=100000 (<=256 required)

  auto align = [](size_t v) { return (v + 255) & ~(size_t)255; };
  char* ws = (char*)d_ws;
  size_t o = 0;
  int* bucket_base = (int*)(ws + o);  o += align((size_t)(nbuck + 1) * 4);
  int* cnt = (int*)(ws + o);          o += align((size_t)GB * nbuck * 4);
  int* cur = (int*)(ws + o);          o += align((size_t)GB * nbuck * 4);
  int* row_ptr = (int*)(ws + o);      o += align((size_t)(N + 1) * 4);
  float* deg_inv = (float*)(ws + o);  o += align((size_t)N * 4);
  int* sorted_src = (int*)(ws + o);   o += align((size_t)E * 4);
  int* tmps = (int*)(ws + o);         o += align((size_t)E * 4);
  u16* tmpd = (u16*)(ws + o);         o += align((size_t)E * 2);
  u8* t1l = (u8*)(ws + o);            o += align((size_t)N * 128);
  u16* t1r = (u16*)(ws + o);          o += align((size_t)N * 128 * 2);
  u16* h = (u16*)(ws + o);            o += align((size_t)N * 128 * 2);
  u8* t3l = t1l;     // aliases: t1 dead once h computed
  u16* t3r = t1r;

  countA_kernel<<<GB, 256, 0, stream>>>(edges, cnt, E, nbuck);
  scanB1_kernel<<<1, 256, 0, stream>>>(cnt, bucket_base, row_ptr, nbuck, N);
  scanB2_kernel<<<nbuck, 256, 0, stream>>>(cnt, bucket_base, cur, nbuck);
  scatterC_kernel<<<GB, 256, 0, stream>>>(edges, cur, tmps, tmpd, E, nbuck);
  finesort_kernel<<<nbuck, 512, 0, stream>>>(tmps, tmpd, bucket_base, row_ptr, deg_inv,
                                             sorted_src, N);

  int mb = (N + 63) / 64;
  // Layer 1: [t1l | t1r] = x @ [W1_l | W1_r]^T  (split=128, nr=128, 2 col-tiles)
  gemm_loop_kernel<false><<<dim3(256, 2), 256, 0, stream>>>(x, W1l, W1r, t1l, t1r, N, 128, 128, mb);
  agg1_kernel<<<(N + 3) / 4, 256, 0, stream>>>(t1l, t1r, row_ptr, sorted_src, deg_inv, b1, h, N);

  // Layer 2: [t3l | t3r] = h @ [W2_l | W2_r]^T  (split=64, nr=64, 1 col-tile)
  gemm_loop_kernel<true><<<dim3(512, 1), 256, 0, stream>>>(h, W2l, W2r, t3l, t3r, N, 64, 64, mb);
  agg2_kernel<<<(N + 3) / 4, 256, 0, stream>>>(t3l, t3r, row_ptr, sorted_src, deg_inv, b2, out, N);
}